// Round 13
// baseline (927.850 us; speedup 1.0000x reference)
//
#include <hip/hip_runtime.h>

#define QLEN 10000
#define TLEN 3000
#define EMB 768
#define HNEED 3
#define NQ (QLEN * HNEED)
#define EG 100000
#define EI 100000
#define DKH 192
#define NHEADS 4

namespace {

typedef unsigned short u16;
typedef unsigned char u8;
typedef unsigned int u32;
typedef __attribute__((ext_vector_type(8))) short bf16x8;
typedef __attribute__((ext_vector_type(4))) float f32x4;
typedef __attribute__((ext_vector_type(2))) float f32x2;

constexpr float SCALE = 0.07216878364870322f; // 1/sqrt(192)
constexpr long long WS = (long long)EMB * EMB;   // 589824
constexpr long long RS = (long long)DKH * DKH;   // 36864

__device__ inline u16 f2bf(float f) {
  unsigned u = __float_as_uint(f);
  unsigned r = (u + 0x7FFFu + ((u >> 16) & 1u)) >> 16;  // RNE
  return (u16)r;
}
__device__ inline float bf2f(u16 h) {
  return __uint_as_float((unsigned)h << 16);
}
__device__ inline u8 f2fp8(float f) {
  u32 pk = __builtin_amdgcn_cvt_pk_fp8_f32(f, f, 0, false);
  return (u8)(pk & 0xFF);
}
__device__ inline void decode12(const u32* p, float* o) {
#pragma unroll
  for (int t = 0; t < 3; ++t) {
    u32 w = p[t];
    f32x2 lo = __builtin_amdgcn_cvt_pk_f32_fp8(w, false);
    f32x2 hi = __builtin_amdgcn_cvt_pk_f32_fp8(w, true);
    o[t * 4 + 0] = lo[0]; o[t * 4 + 1] = lo[1];
    o[t * 4 + 2] = hi[0]; o[t * 4 + 3] = hi[1];
  }
}
__device__ inline f32x2 bfx2(u32 w) {
  f32x2 r;
  r[0] = __uint_as_float(w << 16);
  r[1] = __uint_as_float(w & 0xFFFF0000u);
  return r;
}

__device__ inline void gload_lds16(const u16* g, u16* s) {
  __builtin_amdgcn_global_load_lds(
      (const __attribute__((address_space(1))) unsigned*)g,
      (__attribute__((address_space(3))) unsigned*)s, 16, 0, 0);
}

// ------------------------------------------------------------ bf16 MFMA GEMM
// 128x128 tile, BK=32. A staged via global_load_lds (double-buffer, 16 KB LDS,
// k-chunk swizzle); B fragments loaded GLOBAL->REGISTER (L2-resident weight
// panels), double-buffered across iterations with counted vmcnt(4) so B(t+1)
// stays in flight across the barrier. setprio around MFMA. XCD swizzle.
// OUT: 0=f32, 1=bf16, 2=fp8.
// EPI 0: C[m][n]
// EPI 1: encoder: C_bf[(n/768)*QLEN + m][n%768] = bf16(v + bf2f(extra[m][n%768]))
// EPI 2: merged out: grow<NQ -> Cf[((grow%QLEN)*3+grow/QLEN)*768+n] else direct
// MODE 0: standard z-batch. MODE 1: combine-weights addressing (Wcomb build).
template <int EPI, int OUT, int MODE>
__global__ __launch_bounds__(256) void gemm_bf16(
    const u16* __restrict__ A, int lda, long long sAz,
    const u16* __restrict__ Bt, int ldb, long long sBz,
    void* __restrict__ Cv, int ldc, long long sCz,
    const float* __restrict__ bias, const u16* __restrict__ extra,
    int M, int N, int K)
{
  __shared__ __align__(16) u16 As[2][4096];   // 16 KB total
  const int z = blockIdx.z;
  float* Cf = (float*)Cv;
  u16* Ch = (u16*)Cv;
  u8* C8 = (u8*)Cv;
  if (MODE == 1) {
    const int lr = z >> 3, kv = (z >> 2) & 1, h = z & 3;
    const int l2 = lr >= 3;
    A += (long long)z * RS;
    Bt = (kv ? extra : Bt) + (long long)(l2 * 2) * WS + h * 192;
    Ch = (u16*)Cv + (long long)lr * 1536 * 768 + (long long)(kv * 768 + h * 192) * 768;
  } else {
    A += (long long)z * sAz;
    Bt += (long long)z * sBz;
    Cf += (long long)z * sCz;
    Ch += (long long)z * sCz;
    C8 += (long long)z * sCz;
  }
  // XCD-chunked bijective remap
  const int gx = gridDim.x;
  const int nwg = gx * gridDim.y;
  const int orig = blockIdx.y * gx + blockIdx.x;
  const int qq = nwg >> 3, rr = nwg & 7;
  const int xc = orig & 7, ix = orig >> 3;
  const int swz = (xc < rr ? xc * (qq + 1) : rr * (qq + 1) + (xc - rr) * qq) + ix;
  const int by = swz / gx, bx = swz - by * gx;
  const int bm = by * 128, bn = bx * 128;

  const int tid = threadIdx.x;
  const int w = tid >> 6, l = tid & 63;
  const int wr = w >> 1, wc = w & 1;
  const int l16 = l & 15, lk = l >> 4;
  const int srow = tid >> 2;
  const int scol = (((tid & 3) ^ ((srow >> 1) & 3))) * 8;   // pre-swizzled A chunk
  const int rchunk = (lk ^ ((l16 >> 1) & 3));               // read-side inverse

  int r0 = bm + srow;      if (r0 > M - 1) r0 = M - 1;
  int r1 = bm + srow + 64; if (r1 > M - 1) r1 = M - 1;
  const u16* pa0 = A + (long long)r0 * lda + scol;
  const u16* pa1 = A + (long long)r1 * lda + scol;

  // B fragment pointers (global; clamp col for N-tails — epilogue masks)
  const u16* pB[4];
#pragma unroll
  for (int n = 0; n < 4; ++n) {
    int cb = bn + wc * 64 + n * 16 + l16;
    if (cb > N - 1) cb = N - 1;
    pB[n] = Bt + (long long)cb * ldb + lk * 8;
  }

  int aoff[4];
#pragma unroll
  for (int m = 0; m < 4; ++m)
    aoff[m] = (wr * 64 + m * 16 + l16) * 32 + rchunk * 8;

  f32x4 acc[4][4] = {};
  const int nt = K / 32;

  auto stageA = [&](int buf, int k0) {
    gload_lds16(pa0 + k0, &As[buf][w * 512]);
    gload_lds16(pa1 + k0, &As[buf][w * 512 + 2048]);
  };

  bf16x8 bcur[4], bnxt[4];
  stageA(0, 0);
#pragma unroll
  for (int n = 0; n < 4; ++n) bcur[n] = *(const bf16x8*)(pB[n]);
  asm volatile("s_waitcnt vmcnt(0)" ::: "memory");
  __builtin_amdgcn_s_barrier();
  __builtin_amdgcn_sched_barrier(0);

  int cur = 0;
  for (int t = 0; t < nt; ++t) {
    if (t + 1 < nt) {
      // issue B(t+1) reg loads, keep them in flight across the barrier
#pragma unroll
      for (int n = 0; n < 4; ++n) bnxt[n] = *(const bf16x8*)(pB[n] + (t + 1) * 32);
      asm volatile("s_waitcnt vmcnt(4)" ::: "memory");   // A(t)+B(t) complete
    } else {
      asm volatile("s_waitcnt vmcnt(0)" ::: "memory");
    }
    __builtin_amdgcn_s_barrier();
    __builtin_amdgcn_sched_barrier(0);
    if (t + 1 < nt) stageA(cur ^ 1, (t + 1) * 32);
    bf16x8 af[4];
#pragma unroll
    for (int m = 0; m < 4; ++m)
      af[m] = *(const bf16x8*)&As[cur][aoff[m]];
    __builtin_amdgcn_s_setprio(1);
#pragma unroll
    for (int m = 0; m < 4; ++m)
#pragma unroll
      for (int n = 0; n < 4; ++n)
        acc[m][n] = __builtin_amdgcn_mfma_f32_16x16x32_bf16(af[m], bcur[n], acc[m][n], 0, 0, 0);
    __builtin_amdgcn_s_setprio(0);
    if (t + 1 < nt) {
#pragma unroll
      for (int n = 0; n < 4; ++n) bcur[n] = bnxt[n];
    }
    cur ^= 1;
  }

#pragma unroll
  for (int m = 0; m < 4; ++m) {
#pragma unroll
    for (int j = 0; j < 4; ++j) {
      int grow = bm + wr * 64 + m * 16 + lk * 4 + j;
      if (grow >= M) continue;
#pragma unroll
      for (int n = 0; n < 4; ++n) {
        int gcol2 = bn + wc * 64 + n * 16 + l16;
        if (gcol2 >= N) continue;
        float val = acc[m][n][j] + (bias ? bias[gcol2] : 0.f);
        if (EPI == 0) {
          if (OUT == 0)
            Cf[(long long)grow * ldc + gcol2] = val;
          else if (OUT == 1)
            Ch[(long long)grow * ldc + gcol2] = f2bf(val);
          else
            C8[(long long)grow * ldc + gcol2] = f2fp8(val);
        } else if (EPI == 1) {
          int h = gcol2 / EMB, c = gcol2 - h * EMB;
          Ch[((long long)h * QLEN + grow) * EMB + c] =
              f2bf(val + bf2f(extra[(long long)grow * EMB + c]));
        } else {
          if (grow < NQ) {
            int i2 = grow % QLEN, h = grow / QLEN;
            Cf[((long long)i2 * HNEED + h) * EMB + gcol2] = val;
          } else {
            Cf[(long long)grow * EMB + gcol2] = val;
          }
        }
      }
    }
  }
}

// ------------------------------------------------- grouped per-layer GEMM pack
// All jobs: K=768, lda=ldb=768, N multiple of 128. out: 1=bf16, 2=fp8.
// Same B-in-registers structure as gemm_bf16.
struct PackJobs {
  const u16* A[5];
  const u16* Bt[5];
  void* C[5];
  const float* bias[5];
  int M[5];
  int nx[5];
  int ldc[5];
  int out[5];
  int start[6];
};

__global__ __launch_bounds__(256) void gemm_pack(PackJobs Jb)
{
  const int nwg = Jb.start[5];
  const int orig = blockIdx.x;
  const int qq = nwg >> 3, rr = nwg & 7;
  const int xc = orig & 7, ix = orig >> 3;
  const int swz = (xc < rr ? xc * (qq + 1) : rr * (qq + 1) + (xc - rr) * qq) + ix;
  int j = 0;
  while (swz >= Jb.start[j + 1]) ++j;
  const int local = swz - Jb.start[j];
  const int nx = Jb.nx[j];
  const int by = local / nx, bx = local - by * nx;
  const int bm = by * 128, bn = bx * 128;
  const int M = Jb.M[j];
  const int ldc = Jb.ldc[j];
  const int outk = Jb.out[j];
  const u16* A = Jb.A[j];
  const u16* Bt = Jb.Bt[j];
  const float* bias = Jb.bias[j];
  u16* Ch = (u16*)Jb.C[j];
  u8* C8 = (u8*)Jb.C[j];

  __shared__ __align__(16) u16 As[2][4096];

  const int tid = threadIdx.x;
  const int w = tid >> 6, l = tid & 63;
  const int wr = w >> 1, wc = w & 1;
  const int l16 = l & 15, lk = l >> 4;
  const int srow = tid >> 2;
  const int scol = (((tid & 3) ^ ((srow >> 1) & 3))) * 8;
  const int rchunk = (lk ^ ((l16 >> 1) & 3));

  int r0 = bm + srow;      if (r0 > M - 1) r0 = M - 1;
  int r1 = bm + srow + 64; if (r1 > M - 1) r1 = M - 1;
  const u16* pa0 = A + (long long)r0 * 768 + scol;
  const u16* pa1 = A + (long long)r1 * 768 + scol;

  const u16* pB[4];
#pragma unroll
  for (int n = 0; n < 4; ++n) {
    int cb = bn + wc * 64 + n * 16 + l16;   // N multiple of 128: no clamp
    pB[n] = Bt + (long long)cb * 768 + lk * 8;
  }

  int aoff[4];
#pragma unroll
  for (int m = 0; m < 4; ++m)
    aoff[m] = (wr * 64 + m * 16 + l16) * 32 + rchunk * 8;

  f32x4 acc[4][4] = {};
  const int nt = 24;   // K = 768

  auto stageA = [&](int buf, int k0) {
    gload_lds16(pa0 + k0, &As[buf][w * 512]);
    gload_lds16(pa1 + k0, &As[buf][w * 512 + 2048]);
  };

  bf16x8 bcur[4], bnxt[4];
  stageA(0, 0);
#pragma unroll
  for (int n = 0; n < 4; ++n) bcur[n] = *(const bf16x8*)(pB[n]);
  asm volatile("s_waitcnt vmcnt(0)" ::: "memory");
  __builtin_amdgcn_s_barrier();
  __builtin_amdgcn_sched_barrier(0);

  int cur = 0;
  for (int t = 0; t < nt; ++t) {
    if (t + 1 < nt) {
#pragma unroll
      for (int n = 0; n < 4; ++n) bnxt[n] = *(const bf16x8*)(pB[n] + (t + 1) * 32);
      asm volatile("s_waitcnt vmcnt(4)" ::: "memory");
    } else {
      asm volatile("s_waitcnt vmcnt(0)" ::: "memory");
    }
    __builtin_amdgcn_s_barrier();
    __builtin_amdgcn_sched_barrier(0);
    if (t + 1 < nt) stageA(cur ^ 1, (t + 1) * 32);
    bf16x8 af[4];
#pragma unroll
    for (int m = 0; m < 4; ++m)
      af[m] = *(const bf16x8*)&As[cur][aoff[m]];
    __builtin_amdgcn_s_setprio(1);
#pragma unroll
    for (int m = 0; m < 4; ++m)
#pragma unroll
      for (int n = 0; n < 4; ++n)
        acc[m][n] = __builtin_amdgcn_mfma_f32_16x16x32_bf16(af[m], bcur[n], acc[m][n], 0, 0, 0);
    __builtin_amdgcn_s_setprio(0);
    if (t + 1 < nt) {
#pragma unroll
      for (int n = 0; n < 4; ++n) bcur[n] = bnxt[n];
    }
    cur ^= 1;
  }

#pragma unroll
  for (int m = 0; m < 4; ++m) {
#pragma unroll
    for (int j2 = 0; j2 < 4; ++j2) {
      int grow = bm + wr * 64 + m * 16 + lk * 4 + j2;
      if (grow >= M) continue;
#pragma unroll
      for (int n = 0; n < 4; ++n) {
        int gcol2 = bn + wc * 64 + n * 16 + l16;
        float val = acc[m][n][j2] + bias[gcol2];
        if (outk == 1)
          Ch[(long long)grow * ldc + gcol2] = f2bf(val);
        else
          C8[(long long)grow * ldc + gcol2] = f2fp8(val);
      }
    }
  }
}

// ------------------------------------------------------ conversion kernels
__global__ void f2bf_kernel(const float* __restrict__ in, u16* __restrict__ out, long long n)
{
  long long i = ((long long)blockIdx.x * 256 + threadIdx.x) * 4;
  if (i >= n) return;
  float4 v = *(const float4*)(in + i);
  ushort4 o;
  o.x = f2bf(v.x); o.y = f2bf(v.y); o.z = f2bf(v.z); o.w = f2bf(v.w);
  *(ushort4*)(out + i) = o;
}

// -------- batched 768x768 transposes ----------------
struct T12 {
  const float* s[12];
  u16* d[12];
  int ld[12];
};

__global__ __launch_bounds__(256) void transpose768(T12 jobs)
{
  const int z = blockIdx.z;
  const float* in = jobs.s[z];
  const long long ld = jobs.ld[z];
  u16* out = jobs.d[z];
  __shared__ float t[32][33];
  const int c0 = blockIdx.x * 32, r0 = blockIdx.y * 32;
  const int tx = threadIdx.x & 31, ty = threadIdx.x >> 5;
#pragma unroll
  for (int i = 0; i < 32; i += 8)
    t[ty + i][tx] = in[(long long)(r0 + ty + i) * ld + c0 + tx];
  __syncthreads();
#pragma unroll
  for (int i = 0; i < 32; i += 8)
    out[(long long)(c0 + ty + i) * 768 + r0 + tx] = f2bf(t[tx][ty + i]);
}

// -------- rel weight transpose: z<24 att -> slot lr*8+h ; z>=24 msg -> +4
__global__ __launch_bounds__(256) void transpose_rel(
    const float* __restrict__ att, const float* __restrict__ msg,
    u16* __restrict__ relWT)
{
  const int z = blockIdx.z;
  const int isMsg = z >= 24;
  const int zz = isMsg ? z - 24 : z;
  const int lr = zz >> 2, h = zz & 3;
  const float* in = (isMsg ? msg : att) + (long long)zz * RS;
  u16* out = relWT + (long long)(lr * 8 + isMsg * 4 + h) * RS;
  __shared__ float t[32][33];
  const int c0 = blockIdx.x * 32, r0 = blockIdx.y * 32;
  const int tx = threadIdx.x & 31, ty = threadIdx.x >> 5;
#pragma unroll
  for (int i = 0; i < 32; i += 8)
    t[ty + i][tx] = in[(long long)(r0 + ty + i) * DKH + c0 + tx];
  __syncthreads();
#pragma unroll
  for (int i = 0; i < 32; i += 8)
    out[(long long)(c0 + ty + i) * DKH + r0 + tx] = f2bf(t[tx][ty + i]);
}

// -------- WcT pack --------------------------------------------------------
__global__ void pack_wct(const float* __restrict__ Wc, float* __restrict__ WcT)
{
  int idx = blockIdx.x * 256 + threadIdx.x;
  if (idx >= 7680) return;
  int j = idx / EMB, d = idx - j * EMB;
  WcT[idx] = Wc[d * 10 + j];
}

// -------- bias fold: bcomb[lr][kv*768 + h*192 + j] = sum_e b[e] rel[lr,h,e,j]
__global__ void bcomb_kernel(const float* __restrict__ kb, const float* __restrict__ vb,
                             const float* __restrict__ att, const float* __restrict__ msg,
                             float* __restrict__ bcomb)
{
  int idx = blockIdx.x * 256 + threadIdx.x;
  if (idx >= 6 * 1536) return;
  int lr = idx / 1536, n = idx - lr * 1536;
  int kv = n / 768, n2 = n - kv * 768;
  int h = n2 / 192, j = n2 - h * 192;
  int l = lr / 3;
  const float* bsrc = (kv ? vb : kb) + (l * 2) * EMB + h * 192;
  const float* rl = (kv ? msg : att) + ((long long)lr * 4 + h) * RS + j;
  float s = 0.f;
  for (int e = 0; e < 192; ++e) s = fmaf(bsrc[e], rl[(long long)e * 192], s);
  bcomb[idx] = s;
}

// --------------------------------------------- fused assign-softmax + centers
__global__ __launch_bounds__(512) void assign_center512(
    u16* __restrict__ qh_bf,
    const float* __restrict__ WcT, const float* __restrict__ bc,
    const float* __restrict__ centers)
{
  __shared__ float wc_s[7680];
  __shared__ float cen_s[7680];
  const int tid = threadIdx.x;
  for (int i = tid; i < 7680; i += 512) {
    wc_s[i] = WcT[i];
    cen_s[i] = centers[i];
  }
  __syncthreads();
  const int wave = tid >> 6, lane = tid & 63;
  const int row = blockIdx.x * 8 + wave;
  const long long base = (long long)row * EMB;
  float x[12];
#pragma unroll
  for (int i = 0; i < 12; ++i) x[i] = bf2f(qh_bf[base + lane + 64 * i]);
  float part[10] = {};
#pragma unroll
  for (int i = 0; i < 12; ++i) {
    const float v = x[i];
    const int d = lane + 64 * i;
#pragma unroll
    for (int j = 0; j < 10; ++j) part[j] = fmaf(v, wc_s[j * EMB + d], part[j]);
  }
#pragma unroll
  for (int j = 0; j < 10; ++j)
#pragma unroll
    for (int off = 32; off; off >>= 1) part[j] += __shfl_xor(part[j], off);
  float mx = -1e30f;
#pragma unroll
  for (int j = 0; j < 10; ++j) { part[j] += bc[j]; mx = fmaxf(mx, part[j]); }
  float s = 0.f;
#pragma unroll
  for (int j = 0; j < 10; ++j) { part[j] = __expf(part[j] - mx); s += part[j]; }
  const float inv = 1.f / s;
#pragma unroll
  for (int i = 0; i < 12; ++i) {
    const int d = lane + 64 * i;
    float acc = 0.f;
#pragma unroll
    for (int j = 0; j < 10; ++j) acc = fmaf(part[j], cen_s[j * EMB + d], acc);
    qh_bf[base + d] = f2bf(x[i] + acc * inv);
  }
}

// ------------------------------------------------------------- CSR build
__global__ void hist_all(const int* __restrict__ gd, const int* __restrict__ d1,
                         const int* __restrict__ d2, int* __restrict__ cnt)
{
  int e = blockIdx.x * 256 + threadIdx.x;
  if (e < EG) atomicAdd(&cnt[gd[e]], 1);
  else if (e < EG + EI) atomicAdd(&cnt[QLEN + d1[e - EG]], 1);
  else if (e < EG + 2 * EI) atomicAdd(&cnt[QLEN + TLEN + d2[e - EG - EI]], 1);
}

__global__ __launch_bounds__(1024) void scan3(
    const int* __restrict__ cnt_all, int* __restrict__ rp_g,
    int* __restrict__ rp_1, int* __restrict__ rp_2, int* __restrict__ cur_all)
{
  __shared__ int buf[1024];
  const int b = blockIdx.x;
  const int n = (b == 0) ? QLEN : TLEN;
  const int seg = (b == 0) ? 0 : (b == 1) ? QLEN : QLEN + TLEN;
  const int* cnt = cnt_all + seg;
  int* cur = cur_all + seg;
  int* rowptr = (b == 0) ? rp_g : (b == 1) ? rp_1 : rp_2;
  const int tid = threadIdx.x;
  const int chunk = (n + 1023) >> 10;
  const int base = tid * chunk;
  int s = 0;
  for (int i = 0; i < chunk; ++i) {
    int idx = base + i;
    if (idx < n) s += cnt[idx];
  }
  buf[tid] = s;
  __syncthreads();
  for (int off = 1; off < 1024; off <<= 1) {
    int v = (tid >= off) ? buf[tid - off] : 0;
    __syncthreads();
    buf[tid] += v;
    __syncthreads();
  }
  int run = (tid == 0) ? 0 : buf[tid - 1];
  for (int i = 0; i < chunk; ++i) {
    int idx = base + i;
    if (idx < n) {
      rowptr[idx] = run;
      cur[idx] = run;
      run += cnt[idx];
    }
  }
  if (tid == 1023) rowptr[n] = buf[1023];
}

__global__ void fill_all(const int* __restrict__ gs, const int* __restrict__ gd,
                         const int* __restrict__ s1, const int* __restrict__ d1,
                         const int* __restrict__ s2, const int* __restrict__ d2,
                         int* __restrict__ cur_all, int* __restrict__ adj_all)
{
  int e = blockIdx.x * 256 + threadIdx.x;
  if (e < EG) {
    int p = atomicAdd(&cur_all[gd[e]], 1);
    adj_all[p] = gs[e];
  } else if (e < EG + EI) {
    int p = atomicAdd(&cur_all[QLEN + d1[e - EG]], 1);
    adj_all[EG + p] = s1[e - EG];
  } else if (e < EG + 2 * EI) {
    int p = atomicAdd(&cur_all[QLEN + TLEN + d2[e - EG - EI]], 1);
    adj_all[EG + EI + p] = s2[e - EG - EI];
  }
}

// --------------------- fused gathers: waves [0,QLEN) give, [QLEN,+TLEN) inter
__global__ __launch_bounds__(256) void gather_all(
    const u8* __restrict__ q, const u8* __restrict__ kv_g,
    const int* __restrict__ rp_g, const int* __restrict__ adj_g,
    const float* __restrict__ pri_g, u16* __restrict__ hq_bf,
    const u16* __restrict__ q_tag, const u8* __restrict__ kv1,
    const u8* __restrict__ kv2,
    const int* __restrict__ rp1, const int* __restrict__ adj1,
    const int* __restrict__ rp2, const int* __restrict__ adj2,
    const float* __restrict__ pri1, const float* __restrict__ pri2,
    u16* __restrict__ htag_bf)
{
  const int wid = blockIdx.x * 4 + (threadIdx.x >> 6);
  const int lane = threadIdx.x & 63;
  const int h = lane >> 4, sub = lane & 15;
  const int off = h * DKH + sub * 12;

  if (wid < QLEN) {
    const int d = wid;
    const int rs = rp_g[d], re = rp_g[d + 1];
    if (rs == re) return;
    const float pri = pri_g[h] * SCALE;
    float qv[3][12];
#pragma unroll
    for (int c = 0; c < 3; ++c)
      decode12((const u32*)(q + (size_t)(c * QLEN + d) * EMB + off), qv[c]);
    float S[3] = {0.f, 0.f, 0.f};
    float A[3][12] = {};
    auto edge = [&](int sn) {
      float kf[12], vf[12];
      decode12((const u32*)(kv_g + (size_t)sn * 1536 + off), kf);
      decode12((const u32*)(kv_g + (size_t)sn * 1536 + 768 + off), vf);
      float dt[3] = {0.f, 0.f, 0.f};
#pragma unroll
      for (int t = 0; t < 12; ++t) {
#pragma unroll
        for (int c = 0; c < 3; ++c) dt[c] = fmaf(qv[c][t], kf[t], dt[c]);
      }
#pragma unroll
      for (int c = 0; c < 3; ++c) {
#pragma unroll
        for (int o2 = 8; o2; o2 >>= 1) dt[c] += __shfl_xor(dt[c], o2);
        const float e = __expf(dt[c] * pri);
        S[c] += e;
#pragma unroll
        for (int t = 0; t < 12; ++t) A[c][t] = fmaf(e, vf[t], A[c][t]);
      }
    };
    int i = rs;
    for (; i + 1 < re; i += 2) { edge(adj_g[i]); edge(adj_g[i + 1]); }
    if (i < re) edge(adj_g[i]);
#pragma unroll
    for (int c = 0; c < 3; ++c) {
      const float inv = 1.f / S[c];
      u32* o = (u32*)(hq_bf + (size_t)(c * QLEN + d) * EMB + off);
#pragma unroll
      for (int t = 0; t < 6; ++t) {
        f32x2 r = bfx2(o[t]);
        r[0] += A[c][2 * t] * inv;
        r[1] += A[c][2 * t + 1] * inv;
        o[t] = (u32)f2bf(r[0]) | ((u32)f2bf(r[1]) << 16);
      }
    }
  } else {
    const int d = wid - QLEN;
    if (d >= TLEN) return;
    const int rs1 = rp1[d], re1 = rp1[d + 1];
    const int rs2 = rp2[d], re2 = rp2[d + 1];
    if (rs1 == re1 && rs2 == re2) return;
    float qv[12];
    {
      const u32* qp = (const u32*)(q_tag + (size_t)d * EMB + off);
#pragma unroll
      for (int t = 0; t < 6; ++t) {
        f32x2 r = bfx2(qp[t]);
        qv[2 * t] = r[0]; qv[2 * t + 1] = r[1];
      }
    }
    float R[12] = {};
#pragma unroll
    for (int rel = 0; rel < 2; ++rel) {
      const u8* kv = rel ? kv2 : kv1;
      const int rs = rel ? rs2 : rs1, re = rel ? re2 : re1;
      const int* adj = rel ? adj2 : adj1;
      if (rs == re) continue;
      const float pri = (rel ? pri2[h] : pri1[h]) * SCALE;
      float S = 0.f, A[12] = {};
      auto edge = [&](int sn) {
        float kf[12], vf[12];
        decode12((const u32*)(kv + (size_t)sn * 1536 + off), kf);
        decode12((const u32*)(kv + (size_t)sn * 1536 + 768 + off), vf);
        float dt = 0.f;
#pragma unroll
        for (int t = 0; t < 12; ++t) dt = fmaf(qv[t], kf[t], dt);
#pragma unroll
        for (int o2 = 8; o2; o2 >>= 1) dt += __shfl_xor(dt, o2);
        const float e = __expf(dt * pri);
        S += e;
#pragma unroll
        for (int t = 0; t < 12; ++t) A[t] = fmaf(e, vf[t], A[t]);
      };
      int i = rs;
      for (; i + 1 < re; i += 2) { edge(adj[i]); edge(adj[i + 1]); }
      if (i < re) edge(adj[i]);
      const float inv = 0.5f / S;
#pragma unroll
      for (int t = 0; t < 12; ++t) R[t] = fmaf(A[t], inv, R[t]);
    }
    u32* o = (u32*)(htag_bf + (size_t)d * EMB + off);
#pragma unroll
    for (int t = 0; t < 6; ++t) {
      f32x2 r = bfx2(o[t]);
      r[0] += R[2 * t];
      r[1] += R[2 * t + 1];
      o[t] = (u32)f2bf(r[0]) | ((u32)f2bf(r[1]) << 16);
    }
  }
}

}  // namespace

extern "C" void kernel_launch(void* const* d_in, const int* in_sizes, int n_in,
                              void* d_out, int out_size, void* d_ws, size_t ws_size,
                              hipStream_t stream)
{
  const float* q_emb   = (const float*)d_in[0];
  const float* t_emb   = (const float*)d_in[1];
  const int*   give_src = (const int*)d_in[2];
  const int*   give_dst = (const int*)d_in[3];
  const int*   i1_src  = (const int*)d_in[4];
  const int*   i1_dst  = (const int*)d_in[5];
  const int*   i2_src  = (const int*)d_in[6];
  const int*   i2_dst  = (const int*)d_in[7];
  const float* Wq_enc  = (const float*)d_in[8];
  const float* bq_enc  = (const float*)d_in[9];
  const float* Wc      = (const float*)d_in[10];
  const float* bc      = (const float*)d_in[11];
  const float* centers = (const float*)d_in[12];
  const float* kW      = (const float*)d_in[13];
  const float* kb      = (const float*)d_in[14];
  const float* qW      = (const float*)d_in[15];
  const float* qb      = (const float*)d_in[16];
  const float* vW      = (const float*)d_in[17];
  const float* vb      = (const float*)d_in[18];
  const float* rel_att = (const float*)d_in[19];
  const float* rel_msg = (const float*)d_in[20];
  const float* rel_pri = (const float*)d_in[21];
  const float* Wout    = (const float*)d_in[22];
  const float* bout    = (const float*)d_in[23];
  float* out = (float*)d_out;

  // -------- workspace carve-up
  float* p = (float*)d_ws;
  auto take = [&](size_t n) { float* r = p; p += ((n + 3) & ~(size_t)3); return r; };
  u16* h_q_bf    = (u16*)take((size_t)NQ * EMB / 2);
  u16* h_tag_bf  = (u16*)take((size_t)TLEN * EMB / 2);
  u16* q_emb_bf  = (u16*)take((size_t)QLEN * EMB / 2);
  u16* q_tag_bf  = (u16*)take((size_t)TLEN * EMB / 2);
  u8* kv_all     = (u8*)take((size_t)3 * TLEN * 1536 / 4);
  u8* kv_g = kv_all;
  u8* kv_1 = kv_all + (size_t)TLEN * 1536;
  u8* kv_2 = kv_all + (size_t)2 * TLEN * 1536;
  u16* WqT   = (u16*)take((size_t)3 * WS / 2);
  u16* qWT   = (u16*)take((size_t)4 * WS / 2);
  u16* WoutT = (u16*)take((size_t)WS / 2);
  u16* relWT = (u16*)take((size_t)48 * RS / 2);
  u16* kWbf  = (u16*)take((size_t)4 * WS / 2);
  u16* vWbf  = (u16*)take((size_t)4 * WS / 2);
  u16* Wcomb = (u16*)take((size_t)6 * 1536 * 768 / 2);
  float* bcomb = take(6 * 1536);
  float* WcT   = take(7680);
  int* rp_g  = (int*)take(QLEN + 1);
  int* rp_1  = (int*)take(TLEN + 1);
  int* rp_2  = (int*)take(TLEN + 1);
  int* cur_all = (int*)take(QLEN + 2 * TLEN);
  int* cnt_all = (int*)take(QLEN + 2 * TLEN);
  int* adj_all = (int*)take(EG + 2 * EI);
  int* adj_g = adj_all;
  int* adj_1 = adj_all + EG;
  int* adj_2 = adj_all + EG + EI;
  u8* q_que = (u8*)out;   // d_out as scratch (fp8); fully overwritten at end

  // -------- CSR builds
  hipMemsetAsync(cnt_all, 0, (size_t)(QLEN + 2 * TLEN) * sizeof(int), stream);
  hist_all<<<(EG + 2 * EI + 255) / 256, 256, 0, stream>>>(give_dst, i1_dst, i2_dst, cnt_all);
  scan3<<<3, 1024, 0, stream>>>(cnt_all, rp_g, rp_1, rp_2, cur_all);
  fill_all<<<(EG + 2 * EI + 255) / 256, 256, 0, stream>>>(
      give_src, give_dst, i1_src, i1_dst, i2_src, i2_dst, cur_all, adj_all);

  // -------- weight prep
  pack_wct<<<30, 256, 0, stream>>>(Wc, WcT);
  {
    T12 jobs;
    for (int j = 0; j < 3; ++j) { jobs.s[j] = Wq_enc + j * 768; jobs.d[j] = WqT + (long long)j * WS; jobs.ld[j] = 2304; }
    for (int s = 0; s < 4; ++s) { jobs.s[3 + s] = qW + (long long)s * WS; jobs.d[3 + s] = qWT + (long long)s * WS; jobs.ld[3 + s] = 768; }
    jobs.s[7] = Wout; jobs.d[7] = WoutT; jobs.ld[7] = 768;
    for (int j = 8; j < 12; ++j) { jobs.s[j] = Wout; jobs.d[j] = WoutT; jobs.ld[j] = 768; }
    transpose768<<<dim3(24, 24, 8), 256, 0, stream>>>(jobs);
  }
  transpose_rel<<<dim3(6, 6, 48), 256, 0, stream>>>(rel_att, rel_msg, relWT);
  f2bf_kernel<<<(int)((4 * WS / 4 + 255) / 256), 256, 0, stream>>>(kW, kWbf, 4 * WS);
  f2bf_kernel<<<(int)((4 * WS / 4 + 255) / 256), 256, 0, stream>>>(vW, vWbf, 4 * WS);
  gemm_bf16<0, 1, 1><<<dim3(6, 2, 48), 256, 0, stream>>>(
      relWT, DKH, 0, kWbf, EMB, 0, Wcomb, EMB, 0, nullptr, vWbf, DKH, EMB, DKH);
  bcomb_kernel<<<36, 256, 0, stream>>>(kb, vb, rel_att, rel_msg, bcomb);

  // -------- question encoder + clustering
  f2bf_kernel<<<(QLEN * EMB / 4 + 255) / 256, 256, 0, stream>>>(q_emb, q_emb_bf, (long long)QLEN * EMB);
  gemm_bf16<1, 1, 0><<<dim3(18, 79, 1), 256, 0, stream>>>(
      q_emb_bf, EMB, 0, WqT, EMB, 0, h_q_bf, EMB, 0, bq_enc, q_emb_bf,
      QLEN, EMB * HNEED, EMB);
  assign_center512<<<NQ / 8, 512, 0, stream>>>(h_q_bf, WcT, bc, centers);
  f2bf_kernel<<<(TLEN * EMB / 4 + 255) / 256, 256, 0, stream>>>(t_emb, h_tag_bf, (long long)TLEN * EMB);

  for (int l = 0; l < 2; ++l) {
    PackJobs J;
    J.A[0] = h_tag_bf; J.Bt[0] = qWT + (long long)(l * 2) * WS; J.C[0] = q_tag_bf;
    J.bias[0] = qb + (l * 2) * EMB; J.M[0] = TLEN; J.nx[0] = 6; J.ldc[0] = 768; J.out[0] = 1;
    J.A[1] = h_q_bf; J.Bt[1] = qWT + (long long)(l * 2 + 1) * WS; J.C[1] = q_que;
    J.bias[1] = qb + (l * 2 + 1) * EMB; J.M[1] = NQ; J.nx[1] = 6; J.ldc[1] = 768; J.out[1] = 2;
    for (int r = 0; r < 3; ++r) {
      J.A[2 + r] = h_tag_bf;
      J.Bt[2 + r] = Wcomb + (long long)(l * 3 + r) * 1536 * 768;
      J.C[2 + r] = kv_all + (size_t)r * TLEN * 1536;
      J.bias[2 + r] = bcomb + (l * 3 + r) * 1536;
      J.M[2 + r] = TLEN; J.nx[2 + r] = 12; J.ldc[2 + r] = 1536; J.out[2 + r] = 2;
    }
    J.start[0] = 0;
    J.start[1] = 144;
    J.start[2] = 144 + 1410;
    J.start[3] = 1554 + 288;
    J.start[4] = 1842 + 288;
    J.start[5] = 2130 + 288;
    gemm_pack<<<2418, 256, 0, stream>>>(J);

    gather_all<<<(QLEN + TLEN) / 4 + 1, 256, 0, stream>>>(
        q_que, kv_g, rp_g, adj_g, rel_pri + (l * 3 + 0) * NHEADS, h_q_bf,
        q_tag_bf, kv_1, kv_2, rp_1, adj_1, rp_2, adj_2,
        rel_pri + (l * 3 + 1) * NHEADS, rel_pri + (l * 3 + 2) * NHEADS,
        h_tag_bf);
  }

  // -------- merged output GEMM
  gemm_bf16<2, 0, 0><<<dim3(6, 258, 1), 256, 0, stream>>>(
      h_q_bf, EMB, 0, WoutT, EMB, 0, out, EMB, 0, bout, nullptr,
      NQ + TLEN, EMB, EMB);
}

// Round 14
// 762.175 us; speedup vs baseline: 1.2174x; 1.2174x over previous
//
#include <hip/hip_runtime.h>

#define QLEN 10000
#define TLEN 3000
#define EMB 768
#define HNEED 3
#define NQ (QLEN * HNEED)
#define EG 100000
#define EI 100000
#define DKH 192
#define NHEADS 4

namespace {

typedef unsigned short u16;
typedef unsigned char u8;
typedef unsigned int u32;
typedef __attribute__((ext_vector_type(8))) short bf16x8;
typedef __attribute__((ext_vector_type(4))) float f32x4;
typedef __attribute__((ext_vector_type(2))) float f32x2;

constexpr float SCALE = 0.07216878364870322f; // 1/sqrt(192)
constexpr long long WS = (long long)EMB * EMB;   // 589824
constexpr long long RS = (long long)DKH * DKH;   // 36864

__device__ inline u16 f2bf(float f) {
  unsigned u = __float_as_uint(f);
  unsigned r = (u + 0x7FFFu + ((u >> 16) & 1u)) >> 16;  // RNE
  return (u16)r;
}
__device__ inline float bf2f(u16 h) {
  return __uint_as_float((unsigned)h << 16);
}
__device__ inline u8 f2fp8(float f) {
  u32 pk = __builtin_amdgcn_cvt_pk_fp8_f32(f, f, 0, false);
  return (u8)(pk & 0xFF);
}
__device__ inline void decode12(const u32* p, float* o) {
#pragma unroll
  for (int t = 0; t < 3; ++t) {
    u32 w = p[t];
    f32x2 lo = __builtin_amdgcn_cvt_pk_f32_fp8(w, false);
    f32x2 hi = __builtin_amdgcn_cvt_pk_f32_fp8(w, true);
    o[t * 4 + 0] = lo[0]; o[t * 4 + 1] = lo[1];
    o[t * 4 + 2] = hi[0]; o[t * 4 + 3] = hi[1];
  }
}
__device__ inline f32x2 bfx2(u32 w) {
  f32x2 r;
  r[0] = __uint_as_float(w << 16);
  r[1] = __uint_as_float(w & 0xFFFF0000u);
  return r;
}

__device__ inline void gload_lds16(const u16* g, u16* s) {
  __builtin_amdgcn_global_load_lds(
      (const __attribute__((address_space(1))) unsigned*)g,
      (__attribute__((address_space(3))) unsigned*)s, 16, 0, 0);
}

// ------------------------------------------------------------ bf16 MFMA GEMM
// 128x128 tile, BK=32, 3-stage pipelined LDS, counted vmcnt, XCD swizzle,
// LDS k-chunk swizzle, setprio. OUT: 0=f32, 1=bf16, 2=fp8.
// EPI 0: C[m][n]
// EPI 1: encoder: C_bf[(n/768)*QLEN + m][n%768] = bf16(v + bf2f(extra[m][n%768]))
// EPI 2: merged out: grow<NQ -> Cf[((grow%QLEN)*3+grow/QLEN)*768+n] else direct
// MODE 0: standard z-batch. MODE 1: combine-weights addressing (Wcomb build).
template <int EPI, int OUT, int MODE>
__global__ __launch_bounds__(256) void gemm_bf16(
    const u16* __restrict__ A, int lda, long long sAz,
    const u16* __restrict__ Bt, int ldb, long long sBz,
    void* __restrict__ Cv, int ldc, long long sCz,
    const float* __restrict__ bias, const u16* __restrict__ extra,
    int M, int N, int K)
{
  __shared__ __align__(16) u16 As[3][4096];
  __shared__ __align__(16) u16 Bs[3][4096];
  const int z = blockIdx.z;
  float* Cf = (float*)Cv;
  u16* Ch = (u16*)Cv;
  u8* C8 = (u8*)Cv;
  if (MODE == 1) {
    const int lr = z >> 3, kv = (z >> 2) & 1, h = z & 3;
    const int l2 = lr >= 3;
    A += (long long)z * RS;
    Bt = (kv ? extra : Bt) + (long long)(l2 * 2) * WS + h * 192;
    Ch = (u16*)Cv + (long long)lr * 1536 * 768 + (long long)(kv * 768 + h * 192) * 768;
  } else {
    A += (long long)z * sAz;
    Bt += (long long)z * sBz;
    Cf += (long long)z * sCz;
    Ch += (long long)z * sCz;
    C8 += (long long)z * sCz;
  }
  // XCD-chunked bijective remap
  const int gx = gridDim.x;
  const int nwg = gx * gridDim.y;
  const int orig = blockIdx.y * gx + blockIdx.x;
  const int qq = nwg >> 3, rr = nwg & 7;
  const int xc = orig & 7, ix = orig >> 3;
  const int swz = (xc < rr ? xc * (qq + 1) : rr * (qq + 1) + (xc - rr) * qq) + ix;
  const int by = swz / gx, bx = swz - by * gx;
  const int bm = by * 128, bn = bx * 128;

  const int tid = threadIdx.x;
  const int w = tid >> 6, l = tid & 63;
  const int wr = w >> 1, wc = w & 1;
  const int l16 = l & 15, lk = l >> 4;
  const int srow = tid >> 2;
  const int scol = (((tid & 3) ^ ((srow >> 1) & 3))) * 8;
  const int rchunk = (lk ^ ((l16 >> 1) & 3));

  int r0 = bm + srow;      if (r0 > M - 1) r0 = M - 1;
  int r1 = bm + srow + 64; if (r1 > M - 1) r1 = M - 1;
  int c0 = bn + srow;      if (c0 > N - 1) c0 = N - 1;
  int c1 = bn + srow + 64; if (c1 > N - 1) c1 = N - 1;
  const u16* pa0 = A + (long long)r0 * lda + scol;
  const u16* pa1 = A + (long long)r1 * lda + scol;
  const u16* pb0 = Bt + (long long)c0 * ldb + scol;
  const u16* pb1 = Bt + (long long)c1 * ldb + scol;

  int aoff[4], boff[4];
#pragma unroll
  for (int m = 0; m < 4; ++m) {
    aoff[m] = (wr * 64 + m * 16 + l16) * 32 + rchunk * 8;
    boff[m] = (wc * 64 + m * 16 + l16) * 32 + rchunk * 8;
  }

  f32x4 acc[4][4] = {};
  const int nt = K / 32;

  auto stage = [&](int buf, int k0) {
    gload_lds16(pa0 + k0, &As[buf][w * 512]);
    gload_lds16(pa1 + k0, &As[buf][w * 512 + 2048]);
    gload_lds16(pb0 + k0, &Bs[buf][w * 512]);
    gload_lds16(pb1 + k0, &Bs[buf][w * 512 + 2048]);
  };

  stage(0, 0);
  stage(1, 32);
  int cur = 0, sb = 2;
  for (int t = 0; t < nt; ++t) {
    if (t < nt - 1)
      asm volatile("s_waitcnt vmcnt(4)" ::: "memory");
    else
      asm volatile("s_waitcnt vmcnt(0)" ::: "memory");
    __builtin_amdgcn_s_barrier();
    __builtin_amdgcn_sched_barrier(0);
    if (t + 2 < nt) {
      stage(sb, (t + 2) * 32);
      if (++sb == 3) sb = 0;
    }
    bf16x8 af[4], bf[4];
#pragma unroll
    for (int m = 0; m < 4; ++m)
      af[m] = *(const bf16x8*)&As[cur][aoff[m]];
#pragma unroll
    for (int n = 0; n < 4; ++n)
      bf[n] = *(const bf16x8*)&Bs[cur][boff[n]];
    __builtin_amdgcn_s_setprio(1);
#pragma unroll
    for (int m = 0; m < 4; ++m)
#pragma unroll
      for (int n = 0; n < 4; ++n)
        acc[m][n] = __builtin_amdgcn_mfma_f32_16x16x32_bf16(af[m], bf[n], acc[m][n], 0, 0, 0);
    __builtin_amdgcn_s_setprio(0);
    if (++cur == 3) cur = 0;
  }

#pragma unroll
  for (int m = 0; m < 4; ++m) {
#pragma unroll
    for (int j = 0; j < 4; ++j) {
      int grow = bm + wr * 64 + m * 16 + lk * 4 + j;
      if (grow >= M) continue;
#pragma unroll
      for (int n = 0; n < 4; ++n) {
        int gcol = bn + wc * 64 + n * 16 + l16;
        if (gcol >= N) continue;
        float val = acc[m][n][j] + (bias ? bias[gcol] : 0.f);
        if (EPI == 0) {
          if (OUT == 0)
            Cf[(long long)grow * ldc + gcol] = val;
          else if (OUT == 1)
            Ch[(long long)grow * ldc + gcol] = f2bf(val);
          else
            C8[(long long)grow * ldc + gcol] = f2fp8(val);
        } else if (EPI == 1) {
          int h = gcol / EMB, c = gcol - h * EMB;
          Ch[((long long)h * QLEN + grow) * EMB + c] =
              f2bf(val + bf2f(extra[(long long)grow * EMB + c]));
        } else {
          if (grow < NQ) {
            int i2 = grow % QLEN, h = grow / QLEN;
            Cf[((long long)i2 * HNEED + h) * EMB + gcol] = val;
          } else {
            Cf[(long long)grow * EMB + gcol] = val;
          }
        }
      }
    }
  }
}

// ------------------------------------------------- grouped per-layer GEMM pack
struct PackJobs {
  const u16* A[5];
  const u16* Bt[5];
  void* C[5];
  const float* bias[5];
  int M[5];
  int nx[5];
  int ldc[5];
  int out[5];
  int start[6];
};

__global__ __launch_bounds__(256) void gemm_pack(PackJobs Jb)
{
  const int nwg = Jb.start[5];
  const int orig = blockIdx.x;
  const int qq = nwg >> 3, rr = nwg & 7;
  const int xc = orig & 7, ix = orig >> 3;
  const int swz = (xc < rr ? xc * (qq + 1) : rr * (qq + 1) + (xc - rr) * qq) + ix;
  int j = 0;
  while (swz >= Jb.start[j + 1]) ++j;
  const int local = swz - Jb.start[j];
  const int nx = Jb.nx[j];
  const int by = local / nx, bx = local - by * nx;
  const int bm = by * 128, bn = bx * 128;
  const int M = Jb.M[j];
  const int ldc = Jb.ldc[j];
  const int outk = Jb.out[j];
  const u16* A = Jb.A[j];
  const u16* Bt = Jb.Bt[j];
  const float* bias = Jb.bias[j];
  u16* Ch = (u16*)Jb.C[j];
  u8* C8 = (u8*)Jb.C[j];

  __shared__ __align__(16) u16 As[3][4096];
  __shared__ __align__(16) u16 Bs[3][4096];

  const int tid = threadIdx.x;
  const int w = tid >> 6, l = tid & 63;
  const int wr = w >> 1, wc = w & 1;
  const int l16 = l & 15, lk = l >> 4;
  const int srow = tid >> 2;
  const int scol = (((tid & 3) ^ ((srow >> 1) & 3))) * 8;
  const int rchunk = (lk ^ ((l16 >> 1) & 3));

  int r0 = bm + srow;      if (r0 > M - 1) r0 = M - 1;
  int r1 = bm + srow + 64; if (r1 > M - 1) r1 = M - 1;
  const int c0 = bn + srow;
  const int c1 = bn + srow + 64;
  const u16* pa0 = A + (long long)r0 * 768 + scol;
  const u16* pa1 = A + (long long)r1 * 768 + scol;
  const u16* pb0 = Bt + (long long)c0 * 768 + scol;
  const u16* pb1 = Bt + (long long)c1 * 768 + scol;

  int aoff[4], boff[4];
#pragma unroll
  for (int m = 0; m < 4; ++m) {
    aoff[m] = (wr * 64 + m * 16 + l16) * 32 + rchunk * 8;
    boff[m] = (wc * 64 + m * 16 + l16) * 32 + rchunk * 8;
  }

  f32x4 acc[4][4] = {};
  const int nt = 24;   // K = 768

  auto stage = [&](int buf, int k0) {
    gload_lds16(pa0 + k0, &As[buf][w * 512]);
    gload_lds16(pa1 + k0, &As[buf][w * 512 + 2048]);
    gload_lds16(pb0 + k0, &Bs[buf][w * 512]);
    gload_lds16(pb1 + k0, &Bs[buf][w * 512 + 2048]);
  };

  stage(0, 0);
  stage(1, 32);
  int cur = 0, sb = 2;
  for (int t = 0; t < nt; ++t) {
    if (t < nt - 1)
      asm volatile("s_waitcnt vmcnt(4)" ::: "memory");
    else
      asm volatile("s_waitcnt vmcnt(0)" ::: "memory");
    __builtin_amdgcn_s_barrier();
    __builtin_amdgcn_sched_barrier(0);
    if (t + 2 < nt) {
      stage(sb, (t + 2) * 32);
      if (++sb == 3) sb = 0;
    }
    bf16x8 af[4], bf[4];
#pragma unroll
    for (int m = 0; m < 4; ++m)
      af[m] = *(const bf16x8*)&As[cur][aoff[m]];
#pragma unroll
    for (int n = 0; n < 4; ++n)
      bf[n] = *(const bf16x8*)&Bs[cur][boff[n]];
    __builtin_amdgcn_s_setprio(1);
#pragma unroll
    for (int m = 0; m < 4; ++m)
#pragma unroll
      for (int n = 0; n < 4; ++n)
        acc[m][n] = __builtin_amdgcn_mfma_f32_16x16x32_bf16(af[m], bf[n], acc[m][n], 0, 0, 0);
    __builtin_amdgcn_s_setprio(0);
    if (++cur == 3) cur = 0;
  }

#pragma unroll
  for (int m = 0; m < 4; ++m) {
#pragma unroll
    for (int j2 = 0; j2 < 4; ++j2) {
      int grow = bm + wr * 64 + m * 16 + lk * 4 + j2;
      if (grow >= M) continue;
#pragma unroll
      for (int n = 0; n < 4; ++n) {
        int gcol2 = bn + wc * 64 + n * 16 + l16;
        float val = acc[m][n][j2] + bias[gcol2];
        if (outk == 1)
          Ch[(long long)grow * ldc + gcol2] = f2bf(val);
        else
          C8[(long long)grow * ldc + gcol2] = f2fp8(val);
      }
    }
  }
}

// ------------------------------------------------------ conversion kernels
__global__ void f2bf_kernel(const float* __restrict__ in, u16* __restrict__ out, long long n)
{
  long long i = ((long long)blockIdx.x * 256 + threadIdx.x) * 4;
  if (i >= n) return;
  float4 v = *(const float4*)(in + i);
  ushort4 o;
  o.x = f2bf(v.x); o.y = f2bf(v.y); o.z = f2bf(v.z); o.w = f2bf(v.w);
  *(ushort4*)(out + i) = o;
}

// -------- batched 768x768 transposes ----------------
struct T12 {
  const float* s[12];
  u16* d[12];
  int ld[12];
};

__global__ __launch_bounds__(256) void transpose768(T12 jobs)
{
  const int z = blockIdx.z;
  const float* in = jobs.s[z];
  const long long ld = jobs.ld[z];
  u16* out = jobs.d[z];
  __shared__ float t[32][33];
  const int c0 = blockIdx.x * 32, r0 = blockIdx.y * 32;
  const int tx = threadIdx.x & 31, ty = threadIdx.x >> 5;
#pragma unroll
  for (int i = 0; i < 32; i += 8)
    t[ty + i][tx] = in[(long long)(r0 + ty + i) * ld + c0 + tx];
  __syncthreads();
#pragma unroll
  for (int i = 0; i < 32; i += 8)
    out[(long long)(c0 + ty + i) * 768 + r0 + tx] = f2bf(t[tx][ty + i]);
}

// -------- rel weight transpose: z<24 att -> slot lr*8+h ; z>=24 msg -> +4
__global__ __launch_bounds__(256) void transpose_rel(
    const float* __restrict__ att, const float* __restrict__ msg,
    u16* __restrict__ relWT)
{
  const int z = blockIdx.z;
  const int isMsg = z >= 24;
  const int zz = isMsg ? z - 24 : z;
  const int lr = zz >> 2, h = zz & 3;
  const float* in = (isMsg ? msg : att) + (long long)zz * RS;
  u16* out = relWT + (long long)(lr * 8 + isMsg * 4 + h) * RS;
  __shared__ float t[32][33];
  const int c0 = blockIdx.x * 32, r0 = blockIdx.y * 32;
  const int tx = threadIdx.x & 31, ty = threadIdx.x >> 5;
#pragma unroll
  for (int i = 0; i < 32; i += 8)
    t[ty + i][tx] = in[(long long)(r0 + ty + i) * DKH + c0 + tx];
  __syncthreads();
#pragma unroll
  for (int i = 0; i < 32; i += 8)
    out[(long long)(c0 + ty + i) * DKH + r0 + tx] = f2bf(t[tx][ty + i]);
}

// -------- WcT pack --------------------------------------------------------
__global__ void pack_wct(const float* __restrict__ Wc, float* __restrict__ WcT)
{
  int idx = blockIdx.x * 256 + threadIdx.x;
  if (idx >= 7680) return;
  int j = idx / EMB, d = idx - j * EMB;
  WcT[idx] = Wc[d * 10 + j];
}

// -------- bias fold: bcomb[lr][kv*768 + h*192 + j] = sum_e b[e] rel[lr,h,e,j]
__global__ void bcomb_kernel(const float* __restrict__ kb, const float* __restrict__ vb,
                             const float* __restrict__ att, const float* __restrict__ msg,
                             float* __restrict__ bcomb)
{
  int idx = blockIdx.x * 256 + threadIdx.x;
  if (idx >= 6 * 1536) return;
  int lr = idx / 1536, n = idx - lr * 1536;
  int kv = n / 768, n2 = n - kv * 768;
  int h = n2 / 192, j = n2 - h * 192;
  int l = lr / 3;
  const float* bsrc = (kv ? vb : kb) + (l * 2) * EMB + h * 192;
  const float* rl = (kv ? msg : att) + ((long long)lr * 4 + h) * RS + j;
  float s = 0.f;
  for (int e = 0; e < 192; ++e) s = fmaf(bsrc[e], rl[(long long)e * 192], s);
  bcomb[idx] = s;
}

// --------------------------------------------- fused assign-softmax + centers
__global__ __launch_bounds__(512) void assign_center512(
    u16* __restrict__ qh_bf,
    const float* __restrict__ WcT, const float* __restrict__ bc,
    const float* __restrict__ centers)
{
  __shared__ float wc_s[7680];
  __shared__ float cen_s[7680];
  const int tid = threadIdx.x;
  for (int i = tid; i < 7680; i += 512) {
    wc_s[i] = WcT[i];
    cen_s[i] = centers[i];
  }
  __syncthreads();
  const int wave = tid >> 6, lane = tid & 63;
  const int row = blockIdx.x * 8 + wave;
  const long long base = (long long)row * EMB;
  float x[12];
#pragma unroll
  for (int i = 0; i < 12; ++i) x[i] = bf2f(qh_bf[base + lane + 64 * i]);
  float part[10] = {};
#pragma unroll
  for (int i = 0; i < 12; ++i) {
    const float v = x[i];
    const int d = lane + 64 * i;
#pragma unroll
    for (int j = 0; j < 10; ++j) part[j] = fmaf(v, wc_s[j * EMB + d], part[j]);
  }
#pragma unroll
  for (int j = 0; j < 10; ++j)
#pragma unroll
    for (int off = 32; off; off >>= 1) part[j] += __shfl_xor(part[j], off);
  float mx = -1e30f;
#pragma unroll
  for (int j = 0; j < 10; ++j) { part[j] += bc[j]; mx = fmaxf(mx, part[j]); }
  float s = 0.f;
#pragma unroll
  for (int j = 0; j < 10; ++j) { part[j] = __expf(part[j] - mx); s += part[j]; }
  const float inv = 1.f / s;
#pragma unroll
  for (int i = 0; i < 12; ++i) {
    const int d = lane + 64 * i;
    float acc = 0.f;
#pragma unroll
    for (int j = 0; j < 10; ++j) acc = fmaf(part[j], cen_s[j * EMB + d], acc);
    qh_bf[base + d] = f2bf(x[i] + acc * inv);
  }
}

// ------------------------------------------------------------- CSR build
__global__ void hist_all(const int* __restrict__ gd, const int* __restrict__ d1,
                         const int* __restrict__ d2, int* __restrict__ cnt)
{
  int e = blockIdx.x * 256 + threadIdx.x;
  if (e < EG) atomicAdd(&cnt[gd[e]], 1);
  else if (e < EG + EI) atomicAdd(&cnt[QLEN + d1[e - EG]], 1);
  else if (e < EG + 2 * EI) atomicAdd(&cnt[QLEN + TLEN + d2[e - EG - EI]], 1);
}

__global__ __launch_bounds__(1024) void scan3(
    const int* __restrict__ cnt_all, int* __restrict__ rp_g,
    int* __restrict__ rp_1, int* __restrict__ rp_2, int* __restrict__ cur_all)
{
  __shared__ int buf[1024];
  const int b = blockIdx.x;
  const int n = (b == 0) ? QLEN : TLEN;
  const int seg = (b == 0) ? 0 : (b == 1) ? QLEN : QLEN + TLEN;
  const int* cnt = cnt_all + seg;
  int* cur = cur_all + seg;
  int* rowptr = (b == 0) ? rp_g : (b == 1) ? rp_1 : rp_2;
  const int tid = threadIdx.x;
  const int chunk = (n + 1023) >> 10;
  const int base = tid * chunk;
  int s = 0;
  for (int i = 0; i < chunk; ++i) {
    int idx = base + i;
    if (idx < n) s += cnt[idx];
  }
  buf[tid] = s;
  __syncthreads();
  for (int off = 1; off < 1024; off <<= 1) {
    int v = (tid >= off) ? buf[tid - off] : 0;
    __syncthreads();
    buf[tid] += v;
    __syncthreads();
  }
  int run = (tid == 0) ? 0 : buf[tid - 1];
  for (int i = 0; i < chunk; ++i) {
    int idx = base + i;
    if (idx < n) {
      rowptr[idx] = run;
      cur[idx] = run;
      run += cnt[idx];
    }
  }
  if (tid == 1023) rowptr[n] = buf[1023];
}

__global__ void fill_all(const int* __restrict__ gs, const int* __restrict__ gd,
                         const int* __restrict__ s1, const int* __restrict__ d1,
                         const int* __restrict__ s2, const int* __restrict__ d2,
                         int* __restrict__ cur_all, int* __restrict__ adj_all)
{
  int e = blockIdx.x * 256 + threadIdx.x;
  if (e < EG) {
    int p = atomicAdd(&cur_all[gd[e]], 1);
    adj_all[p] = gs[e];
  } else if (e < EG + EI) {
    int p = atomicAdd(&cur_all[QLEN + d1[e - EG]], 1);
    adj_all[EG + p] = s1[e - EG];
  } else if (e < EG + 2 * EI) {
    int p = atomicAdd(&cur_all[QLEN + TLEN + d2[e - EG - EI]], 1);
    adj_all[EG + EI + p] = s2[e - EG - EI];
  }
}

// --------------------- fused gathers: waves [0,QLEN) give, [QLEN,+TLEN) inter
__global__ __launch_bounds__(256) void gather_all(
    const u8* __restrict__ q, const u8* __restrict__ kv_g,
    const int* __restrict__ rp_g, const int* __restrict__ adj_g,
    const float* __restrict__ pri_g, u16* __restrict__ hq_bf,
    const u16* __restrict__ q_tag, const u8* __restrict__ kv1,
    const u8* __restrict__ kv2,
    const int* __restrict__ rp1, const int* __restrict__ adj1,
    const int* __restrict__ rp2, const int* __restrict__ adj2,
    const float* __restrict__ pri1, const float* __restrict__ pri2,
    u16* __restrict__ htag_bf)
{
  const int wid = blockIdx.x * 4 + (threadIdx.x >> 6);
  const int lane = threadIdx.x & 63;
  const int h = lane >> 4, sub = lane & 15;
  const int off = h * DKH + sub * 12;

  if (wid < QLEN) {
    const int d = wid;
    const int rs = rp_g[d], re = rp_g[d + 1];
    if (rs == re) return;
    const float pri = pri_g[h] * SCALE;
    float qv[3][12];
#pragma unroll
    for (int c = 0; c < 3; ++c)
      decode12((const u32*)(q + (size_t)(c * QLEN + d) * EMB + off), qv[c]);
    float S[3] = {0.f, 0.f, 0.f};
    float A[3][12] = {};
    auto edge = [&](int sn) {
      float kf[12], vf[12];
      decode12((const u32*)(kv_g + (size_t)sn * 1536 + off), kf);
      decode12((const u32*)(kv_g + (size_t)sn * 1536 + 768 + off), vf);
      float dt[3] = {0.f, 0.f, 0.f};
#pragma unroll
      for (int t = 0; t < 12; ++t) {
#pragma unroll
        for (int c = 0; c < 3; ++c) dt[c] = fmaf(qv[c][t], kf[t], dt[c]);
      }
#pragma unroll
      for (int c = 0; c < 3; ++c) {
#pragma unroll
        for (int o2 = 8; o2; o2 >>= 1) dt[c] += __shfl_xor(dt[c], o2);
        const float e = __expf(dt[c] * pri);
        S[c] += e;
#pragma unroll
        for (int t = 0; t < 12; ++t) A[c][t] = fmaf(e, vf[t], A[c][t]);
      }
    };
    __builtin_amdgcn_s_setprio(1);
    int i = rs;
    for (; i + 1 < re; i += 2) { edge(adj_g[i]); edge(adj_g[i + 1]); }
    if (i < re) edge(adj_g[i]);
    __builtin_amdgcn_s_setprio(0);
#pragma unroll
    for (int c = 0; c < 3; ++c) {
      const float inv = 1.f / S[c];
      u32* o = (u32*)(hq_bf + (size_t)(c * QLEN + d) * EMB + off);
#pragma unroll
      for (int t = 0; t < 6; ++t) {
        f32x2 r = bfx2(o[t]);
        r[0] += A[c][2 * t] * inv;
        r[1] += A[c][2 * t + 1] * inv;
        o[t] = (u32)f2bf(r[0]) | ((u32)f2bf(r[1]) << 16);
      }
    }
  } else {
    const int d = wid - QLEN;
    if (d >= TLEN) return;
    const int rs1 = rp1[d], re1 = rp1[d + 1];
    const int rs2 = rp2[d], re2 = rp2[d + 1];
    if (rs1 == re1 && rs2 == re2) return;
    float qv[12];
    {
      const u32* qp = (const u32*)(q_tag + (size_t)d * EMB + off);
#pragma unroll
      for (int t = 0; t < 6; ++t) {
        f32x2 r = bfx2(qp[t]);
        qv[2 * t] = r[0]; qv[2 * t + 1] = r[1];
      }
    }
    float R[12] = {};
#pragma unroll
    for (int rel = 0; rel < 2; ++rel) {
      const u8* kv = rel ? kv2 : kv1;
      const int rs = rel ? rs2 : rs1, re = rel ? re2 : re1;
      const int* adj = rel ? adj2 : adj1;
      if (rs == re) continue;
      const float pri = (rel ? pri2[h] : pri1[h]) * SCALE;
      float S = 0.f, A[12] = {};
      auto edge = [&](int sn) {
        float kf[12], vf[12];
        decode12((const u32*)(kv + (size_t)sn * 1536 + off), kf);
        decode12((const u32*)(kv + (size_t)sn * 1536 + 768 + off), vf);
        float dt = 0.f;
#pragma unroll
        for (int t = 0; t < 12; ++t) dt = fmaf(qv[t], kf[t], dt);
#pragma unroll
        for (int o2 = 8; o2; o2 >>= 1) dt += __shfl_xor(dt, o2);
        const float e = __expf(dt * pri);
        S += e;
#pragma unroll
        for (int t = 0; t < 12; ++t) A[t] = fmaf(e, vf[t], A[t]);
      };
      __builtin_amdgcn_s_setprio(1);
      int i = rs;
      for (; i + 1 < re; i += 2) { edge(adj[i]); edge(adj[i + 1]); }
      if (i < re) edge(adj[i]);
      __builtin_amdgcn_s_setprio(0);
      const float inv = 0.5f / S;
#pragma unroll
      for (int t = 0; t < 12; ++t) R[t] = fmaf(A[t], inv, R[t]);
    }
    u32* o = (u32*)(htag_bf + (size_t)d * EMB + off);
#pragma unroll
    for (int t = 0; t < 6; ++t) {
      f32x2 r = bfx2(o[t]);
      r[0] += R[2 * t];
      r[1] += R[2 * t + 1];
      o[t] = (u32)f2bf(r[0]) | ((u32)f2bf(r[1]) << 16);
    }
  }
}

}  // namespace

extern "C" void kernel_launch(void* const* d_in, const int* in_sizes, int n_in,
                              void* d_out, int out_size, void* d_ws, size_t ws_size,
                              hipStream_t stream)
{
  const float* q_emb   = (const float*)d_in[0];
  const float* t_emb   = (const float*)d_in[1];
  const int*   give_src = (const int*)d_in[2];
  const int*   give_dst = (const int*)d_in[3];
  const int*   i1_src  = (const int*)d_in[4];
  const int*   i1_dst  = (const int*)d_in[5];
  const int*   i2_src  = (const int*)d_in[6];
  const int*   i2_dst  = (const int*)d_in[7];
  const float* Wq_enc  = (const float*)d_in[8];
  const float* bq_enc  = (const float*)d_in[9];
  const float* Wc      = (const float*)d_in[10];
  const float* bc      = (const float*)d_in[11];
  const float* centers = (const float*)d_in[12];
  const float* kW      = (const float*)d_in[13];
  const float* kb      = (const float*)d_in[14];
  const float* qW      = (const float*)d_in[15];
  const float* qb      = (const float*)d_in[16];
  const float* vW      = (const float*)d_in[17];
  const float* vb      = (const float*)d_in[18];
  const float* rel_att = (const float*)d_in[19];
  const float* rel_msg = (const float*)d_in[20];
  const float* rel_pri = (const float*)d_in[21];
  const float* Wout    = (const float*)d_in[22];
  const float* bout    = (const float*)d_in[23];
  float* out = (float*)d_out;

  // -------- workspace carve-up
  float* p = (float*)d_ws;
  auto take = [&](size_t n) { float* r = p; p += ((n + 3) & ~(size_t)3); return r; };
  u16* h_q_bf    = (u16*)take((size_t)NQ * EMB / 2);
  u16* h_tag_bf  = (u16*)take((size_t)TLEN * EMB / 2);
  u16* q_emb_bf  = (u16*)take((size_t)QLEN * EMB / 2);
  u16* q_tag_bf  = (u16*)take((size_t)TLEN * EMB / 2);
  u8* kv_all     = (u8*)take((size_t)3 * TLEN * 1536 / 4);
  u8* kv_g = kv_all;
  u8* kv_1 = kv_all + (size_t)TLEN * 1536;
  u8* kv_2 = kv_all + (size_t)2 * TLEN * 1536;
  u16* WqT   = (u16*)take((size_t)3 * WS / 2);
  u16* qWT   = (u16*)take((size_t)4 * WS / 2);
  u16* WoutT = (u16*)take((size_t)WS / 2);
  u16* relWT = (u16*)take((size_t)48 * RS / 2);
  u16* kWbf  = (u16*)take((size_t)4 * WS / 2);
  u16* vWbf  = (u16*)take((size_t)4 * WS / 2);
  u16* Wcomb = (u16*)take((size_t)6 * 1536 * 768 / 2);
  float* bcomb = take(6 * 1536);
  float* WcT   = take(7680);
  int* rp_g  = (int*)take(QLEN + 1);
  int* rp_1  = (int*)take(TLEN + 1);
  int* rp_2  = (int*)take(TLEN + 1);
  int* cur_all = (int*)take(QLEN + 2 * TLEN);
  int* cnt_all = (int*)take(QLEN + 2 * TLEN);
  int* adj_all = (int*)take(EG + 2 * EI);
  int* adj_g = adj_all;
  int* adj_1 = adj_all + EG;
  int* adj_2 = adj_all + EG + EI;
  u8* q_que = (u8*)out;   // d_out as scratch (fp8); fully overwritten at end

  // -------- CSR builds
  hipMemsetAsync(cnt_all, 0, (size_t)(QLEN + 2 * TLEN) * sizeof(int), stream);
  hist_all<<<(EG + 2 * EI + 255) / 256, 256, 0, stream>>>(give_dst, i1_dst, i2_dst, cnt_all);
  scan3<<<3, 1024, 0, stream>>>(cnt_all, rp_g, rp_1, rp_2, cur_all);
  fill_all<<<(EG + 2 * EI + 255) / 256, 256, 0, stream>>>(
      give_src, give_dst, i1_src, i1_dst, i2_src, i2_dst, cur_all, adj_all);

  // -------- weight prep
  pack_wct<<<30, 256, 0, stream>>>(Wc, WcT);
  {
    T12 jobs;
    for (int j = 0; j < 3; ++j) { jobs.s[j] = Wq_enc + j * 768; jobs.d[j] = WqT + (long long)j * WS; jobs.ld[j] = 2304; }
    for (int s = 0; s < 4; ++s) { jobs.s[3 + s] = qW + (long long)s * WS; jobs.d[3 + s] = qWT + (long long)s * WS; jobs.ld[3 + s] = 768; }
    jobs.s[7] = Wout; jobs.d[7] = WoutT; jobs.ld[7] = 768;
    for (int j = 8; j < 12; ++j) { jobs.s[j] = Wout; jobs.d[j] = WoutT; jobs.ld[j] = 768; }
    transpose768<<<dim3(24, 24, 8), 256, 0, stream>>>(jobs);
  }
  transpose_rel<<<dim3(6, 6, 48), 256, 0, stream>>>(rel_att, rel_msg, relWT);
  f2bf_kernel<<<(int)((4 * WS / 4 + 255) / 256), 256, 0, stream>>>(kW, kWbf, 4 * WS);
  f2bf_kernel<<<(int)((4 * WS / 4 + 255) / 256), 256, 0, stream>>>(vW, vWbf, 4 * WS);
  gemm_bf16<0, 1, 1><<<dim3(6, 2, 48), 256, 0, stream>>>(
      relWT, DKH, 0, kWbf, EMB, 0, Wcomb, EMB, 0, nullptr, vWbf, DKH, EMB, DKH);
  bcomb_kernel<<<36, 256, 0, stream>>>(kb, vb, rel_att, rel_msg, bcomb);

  // -------- question encoder + clustering
  f2bf_kernel<<<(QLEN * EMB / 4 + 255) / 256, 256, 0, stream>>>(q_emb, q_emb_bf, (long long)QLEN * EMB);
  gemm_bf16<1, 1, 0><<<dim3(18, 79, 1), 256, 0, stream>>>(
      q_emb_bf, EMB, 0, WqT, EMB, 0, h_q_bf, EMB, 0, bq_enc, q_emb_bf,
      QLEN, EMB * HNEED, EMB);
  assign_center512<<<NQ / 8, 512, 0, stream>>>(h_q_bf, WcT, bc, centers);
  f2bf_kernel<<<(TLEN * EMB / 4 + 255) / 256, 256, 0, stream>>>(t_emb, h_tag_bf, (long long)TLEN * EMB);

  for (int l = 0; l < 2; ++l) {
    PackJobs J;
    J.A[0] = h_tag_bf; J.Bt[0] = qWT + (long long)(l * 2) * WS; J.C[0] = q_tag_bf;
    J.bias[0] = qb + (l * 2) * EMB; J.M[0] = TLEN; J.nx[0] = 6; J.ldc[0] = 768; J.out[0] = 1;
    J.A[1] = h_q_bf; J.Bt[1] = qWT + (long long)(l * 2 + 1) * WS; J.C[1] = q_que;
    J.bias[1] = qb + (l * 2 + 1) * EMB; J.M[1] = NQ; J.nx[1] = 6; J.ldc[1] = 768; J.out[1] = 2;
    for (int r = 0; r < 3; ++r) {
      J.A[2 + r] = h_tag_bf;
      J.Bt[2 + r] = Wcomb + (long long)(l * 3 + r) * 1536 * 768;
      J.C[2 + r] = kv_all + (size_t)r * TLEN * 1536;
      J.bias[2 + r] = bcomb + (l * 3 + r) * 1536;
      J.M[2 + r] = TLEN; J.nx[2 + r] = 12; J.ldc[2 + r] = 1536; J.out[2 + r] = 2;
    }
    J.start[0] = 0;
    J.start[1] = 144;
    J.start[2] = 144 + 1410;
    J.start[3] = 1554 + 288;
    J.start[4] = 1842 + 288;
    J.start[5] = 2130 + 288;
    gemm_pack<<<2418, 256, 0, stream>>>(J);

    gather_all<<<(QLEN + TLEN) / 4 + 1, 256, 0, stream>>>(
        q_que, kv_g, rp_g, adj_g, rel_pri + (l * 3 + 0) * NHEADS, h_q_bf,
        q_tag_bf, kv_1, kv_2, rp_1, adj_1, rp_2, adj_2,
        rel_pri + (l * 3 + 1) * NHEADS, rel_pri + (l * 3 + 2) * NHEADS,
        h_tag_bf);
  }

  // -------- merged output GEMM
  gemm_bf16<2, 0, 0><<<dim3(6, 258, 1), 256, 0, stream>>>(
      h_q_bf, EMB, 0, WoutT, EMB, 0, out, EMB, 0, bout, nullptr,
      NQ + TLEN, EMB, EMB);
}

// Round 15
// 743.883 us; speedup vs baseline: 1.2473x; 1.0246x over previous
//
#include <hip/hip_runtime.h>

#define QLEN 10000
#define TLEN 3000
#define EMB 768
#define HNEED 3
#define NQ (QLEN * HNEED)
#define EG 100000
#define EI 100000
#define DKH 192
#define NHEADS 4

namespace {

typedef unsigned short u16;
typedef unsigned char u8;
typedef unsigned int u32;
typedef __attribute__((ext_vector_type(8))) short bf16x8;
typedef __attribute__((ext_vector_type(4))) float f32x4;
typedef __attribute__((ext_vector_type(2))) float f32x2;

constexpr float SCALE = 0.07216878364870322f; // 1/sqrt(192)
constexpr long long WS = (long long)EMB * EMB;   // 589824
constexpr long long RS = (long long)DKH * DKH;   // 36864

__device__ inline u16 f2bf(float f) {
  unsigned u = __float_as_uint(f);
  unsigned r = (u + 0x7FFFu + ((u >> 16) & 1u)) >> 16;  // RNE
  return (u16)r;
}
__device__ inline float bf2f(u16 h) {
  return __uint_as_float((unsigned)h << 16);
}
__device__ inline u8 f2fp8(float f) {
  u32 pk = __builtin_amdgcn_cvt_pk_fp8_f32(f, f, 0, false);
  return (u8)(pk & 0xFF);
}
__device__ inline void decode12(const u32* p, float* o) {
#pragma unroll
  for (int t = 0; t < 3; ++t) {
    u32 w = p[t];
    f32x2 lo = __builtin_amdgcn_cvt_pk_f32_fp8(w, false);
    f32x2 hi = __builtin_amdgcn_cvt_pk_f32_fp8(w, true);
    o[t * 4 + 0] = lo[0]; o[t * 4 + 1] = lo[1];
    o[t * 4 + 2] = hi[0]; o[t * 4 + 3] = hi[1];
  }
}
__device__ inline f32x2 bfx2(u32 w) {
  f32x2 r;
  r[0] = __uint_as_float(w << 16);
  r[1] = __uint_as_float(w & 0xFFFF0000u);
  return r;
}

__device__ inline void gload_lds16(const u16* g, u16* s) {
  __builtin_amdgcn_global_load_lds(
      (const __attribute__((address_space(1))) unsigned*)g,
      (__attribute__((address_space(3))) unsigned*)s, 16, 0, 0);
}

// ------------------------------------------------------------ bf16 MFMA GEMM
// 128x128 tile, BK=32, 3-stage pipelined LDS, counted vmcnt, XCD swizzle,
// LDS k-chunk swizzle, setprio. OUT: 0=f32, 1=bf16, 2=fp8.
// EPI 0: C[m][n]
// EPI 1: encoder: C_bf[(n/768)*QLEN + m][n%768] = bf16(v + bf2f(extra[m][n%768]))
// EPI 2: merged out: grow<NQ -> Cf[((grow%QLEN)*3+grow/QLEN)*768+n] else direct
// MODE 0: standard z-batch. MODE 1: combine-weights addressing (Wcomb build).
template <int EPI, int OUT, int MODE>
__global__ __launch_bounds__(256) void gemm_bf16(
    const u16* __restrict__ A, int lda, long long sAz,
    const u16* __restrict__ Bt, int ldb, long long sBz,
    void* __restrict__ Cv, int ldc, long long sCz,
    const float* __restrict__ bias, const u16* __restrict__ extra,
    int M, int N, int K)
{
  __shared__ __align__(16) u16 As[3][4096];
  __shared__ __align__(16) u16 Bs[3][4096];
  const int z = blockIdx.z;
  float* Cf = (float*)Cv;
  u16* Ch = (u16*)Cv;
  u8* C8 = (u8*)Cv;
  if (MODE == 1) {
    const int lr = z >> 3, kv = (z >> 2) & 1, h = z & 3;
    const int l2 = lr >= 3;
    A += (long long)z * RS;
    Bt = (kv ? extra : Bt) + (long long)(l2 * 2) * WS + h * 192;
    Ch = (u16*)Cv + (long long)lr * 1536 * 768 + (long long)(kv * 768 + h * 192) * 768;
  } else {
    A += (long long)z * sAz;
    Bt += (long long)z * sBz;
    Cf += (long long)z * sCz;
    Ch += (long long)z * sCz;
    C8 += (long long)z * sCz;
  }
  // XCD-chunked bijective remap
  const int gx = gridDim.x;
  const int nwg = gx * gridDim.y;
  const int orig = blockIdx.y * gx + blockIdx.x;
  const int qq = nwg >> 3, rr = nwg & 7;
  const int xc = orig & 7, ix = orig >> 3;
  const int swz = (xc < rr ? xc * (qq + 1) : rr * (qq + 1) + (xc - rr) * qq) + ix;
  const int by = swz / gx, bx = swz - by * gx;
  const int bm = by * 128, bn = bx * 128;

  const int tid = threadIdx.x;
  const int w = tid >> 6, l = tid & 63;
  const int wr = w >> 1, wc = w & 1;
  const int l16 = l & 15, lk = l >> 4;
  const int srow = tid >> 2;
  const int scol = (((tid & 3) ^ ((srow >> 1) & 3))) * 8;
  const int rchunk = (lk ^ ((l16 >> 1) & 3));

  int r0 = bm + srow;      if (r0 > M - 1) r0 = M - 1;
  int r1 = bm + srow + 64; if (r1 > M - 1) r1 = M - 1;
  int c0 = bn + srow;      if (c0 > N - 1) c0 = N - 1;
  int c1 = bn + srow + 64; if (c1 > N - 1) c1 = N - 1;
  const u16* pa0 = A + (long long)r0 * lda + scol;
  const u16* pa1 = A + (long long)r1 * lda + scol;
  const u16* pb0 = Bt + (long long)c0 * ldb + scol;
  const u16* pb1 = Bt + (long long)c1 * ldb + scol;

  int aoff[4], boff[4];
#pragma unroll
  for (int m = 0; m < 4; ++m) {
    aoff[m] = (wr * 64 + m * 16 + l16) * 32 + rchunk * 8;
    boff[m] = (wc * 64 + m * 16 + l16) * 32 + rchunk * 8;
  }

  f32x4 acc[4][4] = {};
  const int nt = K / 32;

  auto stage = [&](int buf, int k0) {
    gload_lds16(pa0 + k0, &As[buf][w * 512]);
    gload_lds16(pa1 + k0, &As[buf][w * 512 + 2048]);
    gload_lds16(pb0 + k0, &Bs[buf][w * 512]);
    gload_lds16(pb1 + k0, &Bs[buf][w * 512 + 2048]);
  };

  stage(0, 0);
  stage(1, 32);
  int cur = 0, sb = 2;
  for (int t = 0; t < nt; ++t) {
    if (t < nt - 1)
      asm volatile("s_waitcnt vmcnt(4)" ::: "memory");
    else
      asm volatile("s_waitcnt vmcnt(0)" ::: "memory");
    __builtin_amdgcn_s_barrier();
    __builtin_amdgcn_sched_barrier(0);
    if (t + 2 < nt) {
      stage(sb, (t + 2) * 32);
      if (++sb == 3) sb = 0;
    }
    bf16x8 af[4], bf[4];
#pragma unroll
    for (int m = 0; m < 4; ++m)
      af[m] = *(const bf16x8*)&As[cur][aoff[m]];
#pragma unroll
    for (int n = 0; n < 4; ++n)
      bf[n] = *(const bf16x8*)&Bs[cur][boff[n]];
    __builtin_amdgcn_s_setprio(1);
#pragma unroll
    for (int m = 0; m < 4; ++m)
#pragma unroll
      for (int n = 0; n < 4; ++n)
        acc[m][n] = __builtin_amdgcn_mfma_f32_16x16x32_bf16(af[m], bf[n], acc[m][n], 0, 0, 0);
    __builtin_amdgcn_s_setprio(0);
    if (++cur == 3) cur = 0;
  }

#pragma unroll
  for (int m = 0; m < 4; ++m) {
#pragma unroll
    for (int j = 0; j < 4; ++j) {
      int grow = bm + wr * 64 + m * 16 + lk * 4 + j;
      if (grow >= M) continue;
#pragma unroll
      for (int n = 0; n < 4; ++n) {
        int gcol = bn + wc * 64 + n * 16 + l16;
        if (gcol >= N) continue;
        float val = acc[m][n][j] + (bias ? bias[gcol] : 0.f);
        if (EPI == 0) {
          if (OUT == 0)
            Cf[(long long)grow * ldc + gcol] = val;
          else if (OUT == 1)
            Ch[(long long)grow * ldc + gcol] = f2bf(val);
          else
            C8[(long long)grow * ldc + gcol] = f2fp8(val);
        } else if (EPI == 1) {
          int h = gcol / EMB, c = gcol - h * EMB;
          Ch[((long long)h * QLEN + grow) * EMB + c] =
              f2bf(val + bf2f(extra[(long long)grow * EMB + c]));
        } else {
          if (grow < NQ) {
            int i2 = grow % QLEN, h = grow / QLEN;
            Cf[((long long)i2 * HNEED + h) * EMB + gcol] = val;
          } else {
            Cf[(long long)grow * EMB + gcol] = val;
          }
        }
      }
    }
  }
}

// ------------------------------------------------- grouped per-layer GEMM pack
struct PackJobs {
  const u16* A[5];
  const u16* Bt[5];
  void* C[5];
  const float* bias[5];
  int M[5];
  int nx[5];
  int ldc[5];
  int out[5];
  int start[6];
};

__global__ __launch_bounds__(256) void gemm_pack(PackJobs Jb)
{
  const int nwg = Jb.start[5];
  const int orig = blockIdx.x;
  const int qq = nwg >> 3, rr = nwg & 7;
  const int xc = orig & 7, ix = orig >> 3;
  const int swz = (xc < rr ? xc * (qq + 1) : rr * (qq + 1) + (xc - rr) * qq) + ix;
  int j = 0;
  while (swz >= Jb.start[j + 1]) ++j;
  const int local = swz - Jb.start[j];
  const int nx = Jb.nx[j];
  const int by = local / nx, bx = local - by * nx;
  const int bm = by * 128, bn = bx * 128;
  const int M = Jb.M[j];
  const int ldc = Jb.ldc[j];
  const int outk = Jb.out[j];
  const u16* A = Jb.A[j];
  const u16* Bt = Jb.Bt[j];
  const float* bias = Jb.bias[j];
  u16* Ch = (u16*)Jb.C[j];
  u8* C8 = (u8*)Jb.C[j];

  __shared__ __align__(16) u16 As[3][4096];
  __shared__ __align__(16) u16 Bs[3][4096];

  const int tid = threadIdx.x;
  const int w = tid >> 6, l = tid & 63;
  const int wr = w >> 1, wc = w & 1;
  const int l16 = l & 15, lk = l >> 4;
  const int srow = tid >> 2;
  const int scol = (((tid & 3) ^ ((srow >> 1) & 3))) * 8;
  const int rchunk = (lk ^ ((l16 >> 1) & 3));

  int r0 = bm + srow;      if (r0 > M - 1) r0 = M - 1;
  int r1 = bm + srow + 64; if (r1 > M - 1) r1 = M - 1;
  const int c0 = bn + srow;
  const int c1 = bn + srow + 64;
  const u16* pa0 = A + (long long)r0 * 768 + scol;
  const u16* pa1 = A + (long long)r1 * 768 + scol;
  const u16* pb0 = Bt + (long long)c0 * 768 + scol;
  const u16* pb1 = Bt + (long long)c1 * 768 + scol;

  int aoff[4], boff[4];
#pragma unroll
  for (int m = 0; m < 4; ++m) {
    aoff[m] = (wr * 64 + m * 16 + l16) * 32 + rchunk * 8;
    boff[m] = (wc * 64 + m * 16 + l16) * 32 + rchunk * 8;
  }

  f32x4 acc[4][4] = {};
  const int nt = 24;   // K = 768

  auto stage = [&](int buf, int k0) {
    gload_lds16(pa0 + k0, &As[buf][w * 512]);
    gload_lds16(pa1 + k0, &As[buf][w * 512 + 2048]);
    gload_lds16(pb0 + k0, &Bs[buf][w * 512]);
    gload_lds16(pb1 + k0, &Bs[buf][w * 512 + 2048]);
  };

  stage(0, 0);
  stage(1, 32);
  int cur = 0, sb = 2;
  for (int t = 0; t < nt; ++t) {
    if (t < nt - 1)
      asm volatile("s_waitcnt vmcnt(4)" ::: "memory");
    else
      asm volatile("s_waitcnt vmcnt(0)" ::: "memory");
    __builtin_amdgcn_s_barrier();
    __builtin_amdgcn_sched_barrier(0);
    if (t + 2 < nt) {
      stage(sb, (t + 2) * 32);
      if (++sb == 3) sb = 0;
    }
    bf16x8 af[4], bf[4];
#pragma unroll
    for (int m = 0; m < 4; ++m)
      af[m] = *(const bf16x8*)&As[cur][aoff[m]];
#pragma unroll
    for (int n = 0; n < 4; ++n)
      bf[n] = *(const bf16x8*)&Bs[cur][boff[n]];
    __builtin_amdgcn_s_setprio(1);
#pragma unroll
    for (int m = 0; m < 4; ++m)
#pragma unroll
      for (int n = 0; n < 4; ++n)
        acc[m][n] = __builtin_amdgcn_mfma_f32_16x16x32_bf16(af[m], bf[n], acc[m][n], 0, 0, 0);
    __builtin_amdgcn_s_setprio(0);
    if (++cur == 3) cur = 0;
  }

#pragma unroll
  for (int m = 0; m < 4; ++m) {
#pragma unroll
    for (int j2 = 0; j2 < 4; ++j2) {
      int grow = bm + wr * 64 + m * 16 + lk * 4 + j2;
      if (grow >= M) continue;
#pragma unroll
      for (int n = 0; n < 4; ++n) {
        int gcol2 = bn + wc * 64 + n * 16 + l16;
        float val = acc[m][n][j2] + bias[gcol2];
        if (outk == 1)
          Ch[(long long)grow * ldc + gcol2] = f2bf(val);
        else
          C8[(long long)grow * ldc + gcol2] = f2fp8(val);
      }
    }
  }
}

// ------------------------------------------------- fused prologue (one launch)
// blocks [0,4608): 8x 768x768 transposes (f32->bf16^T)
// [4608,6336): rel transposes  [6336,8640): f2bf kW  [8640,10944): f2bf vW
// [10944,18444): f2bf q_emb    [18444,20694): f2bf t_emb
// [20694,20724): WcT pack      [20724,20760): bcomb
struct PrepArgs {
  const float *Wq_enc, *qW, *Wout, *kW, *vW, *rel_att, *rel_msg, *Wc, *kb, *vb,
              *q_emb, *t_emb;
  u16 *WqT, *qWT, *WoutT, *relWT, *kWbf, *vWbf, *q_emb_bf, *h_tag_bf;
  float *WcT, *bcomb;
};

__global__ __launch_bounds__(256) void prep_all(PrepArgs P)
{
  __shared__ float t[32][33];
  const int b = blockIdx.x;
  const int tid = threadIdx.x;

  if (b < 4608) {               // ---- 8 x 768x768 transpose slices
    const int z = b / 576, rem = b - z * 576;
    const int bx = rem % 24, by = rem / 24;
    const float* in;
    u16* out;
    long long ld;
    if (z < 3)      { in = P.Wq_enc + z * 768; out = P.WqT + (long long)z * WS; ld = 2304; }
    else if (z < 7) { in = P.qW + (long long)(z - 3) * WS; out = P.qWT + (long long)(z - 3) * WS; ld = 768; }
    else            { in = P.Wout; out = P.WoutT; ld = 768; }
    const int c0 = bx * 32, r0 = by * 32;
    const int tx = tid & 31, ty = tid >> 5;
#pragma unroll
    for (int i = 0; i < 32; i += 8)
      t[ty + i][tx] = in[(long long)(r0 + ty + i) * ld + c0 + tx];
    __syncthreads();
#pragma unroll
    for (int i = 0; i < 32; i += 8)
      out[(long long)(c0 + ty + i) * 768 + r0 + tx] = f2bf(t[tx][ty + i]);
  } else if (b < 6336) {        // ---- rel weight transposes (48 x 192x192)
    const int lb = b - 4608;
    const int z = lb / 36, rem = lb - z * 36;
    const int bx = rem % 6, by = rem / 6;
    const int isMsg = z >= 24;
    const int zz = isMsg ? z - 24 : z;
    const int lr = zz >> 2, h = zz & 3;
    const float* in = (isMsg ? P.rel_msg : P.rel_att) + (long long)zz * RS;
    u16* out = P.relWT + (long long)(lr * 8 + isMsg * 4 + h) * RS;
    const int c0 = bx * 32, r0 = by * 32;
    const int tx = tid & 31, ty = tid >> 5;
#pragma unroll
    for (int i = 0; i < 32; i += 8)
      t[ty + i][tx] = in[(long long)(r0 + ty + i) * DKH + c0 + tx];
    __syncthreads();
#pragma unroll
    for (int i = 0; i < 32; i += 8)
      out[(long long)(c0 + ty + i) * DKH + r0 + tx] = f2bf(t[tx][ty + i]);
  } else if (b < 10944) {       // ---- f2bf kW / vW (4*WS each)
    const int lb = b - 6336;
    const int isV = lb >= 2304;
    const long long i = ((long long)(isV ? lb - 2304 : lb) * 256 + tid) * 4;
    const float* in = isV ? P.vW : P.kW;
    u16* out = isV ? P.vWbf : P.kWbf;
    float4 v = *(const float4*)(in + i);
    ushort4 o;
    o.x = f2bf(v.x); o.y = f2bf(v.y); o.z = f2bf(v.z); o.w = f2bf(v.w);
    *(ushort4*)(out + i) = o;
  } else if (b < 18444) {       // ---- f2bf q_emb (7.68M)
    const long long i = ((long long)(b - 10944) * 256 + tid) * 4;
    float4 v = *(const float4*)(P.q_emb + i);
    ushort4 o;
    o.x = f2bf(v.x); o.y = f2bf(v.y); o.z = f2bf(v.z); o.w = f2bf(v.w);
    *(ushort4*)(P.q_emb_bf + i) = o;
  } else if (b < 20694) {       // ---- f2bf t_emb -> h_tag_bf (2.304M)
    const long long i = ((long long)(b - 18444) * 256 + tid) * 4;
    float4 v = *(const float4*)(P.t_emb + i);
    ushort4 o;
    o.x = f2bf(v.x); o.y = f2bf(v.y); o.z = f2bf(v.z); o.w = f2bf(v.w);
    *(ushort4*)(P.h_tag_bf + i) = o;
  } else if (b < 20724) {       // ---- WcT pack (7680)
    const int idx = (b - 20694) * 256 + tid;
    const int j = idx / EMB, d = idx - j * EMB;
    P.WcT[idx] = P.Wc[d * 10 + j];
  } else {                      // ---- bcomb (9216)
    const int idx = (b - 20724) * 256 + tid;
    const int lr = idx / 1536, n = idx - lr * 1536;
    const int kv = n / 768, n2 = n - kv * 768;
    const int h = n2 / 192, jj = n2 - h * 192;
    const int l = lr / 3;
    const float* bsrc = (kv ? P.vb : P.kb) + (l * 2) * EMB + h * 192;
    const float* rl = (kv ? P.rel_msg : P.rel_att) + ((long long)lr * 4 + h) * RS + jj;
    float s = 0.f;
    for (int e = 0; e < 192; ++e) s = fmaf(bsrc[e], rl[(long long)e * 192], s);
    P.bcomb[idx] = s;
  }
}

// --------------------------------------------- fused assign-softmax + centers
__global__ __launch_bounds__(512) void assign_center512(
    u16* __restrict__ qh_bf,
    const float* __restrict__ WcT, const float* __restrict__ bc,
    const float* __restrict__ centers)
{
  __shared__ float wc_s[7680];
  __shared__ float cen_s[7680];
  const int tid = threadIdx.x;
  for (int i = tid; i < 7680; i += 512) {
    wc_s[i] = WcT[i];
    cen_s[i] = centers[i];
  }
  __syncthreads();
  const int wave = tid >> 6, lane = tid & 63;
  const int row = blockIdx.x * 8 + wave;
  const long long base = (long long)row * EMB;
  float x[12];
#pragma unroll
  for (int i = 0; i < 12; ++i) x[i] = bf2f(qh_bf[base + lane + 64 * i]);
  float part[10] = {};
#pragma unroll
  for (int i = 0; i < 12; ++i) {
    const float v = x[i];
    const int d = lane + 64 * i;
#pragma unroll
    for (int j = 0; j < 10; ++j) part[j] = fmaf(v, wc_s[j * EMB + d], part[j]);
  }
#pragma unroll
  for (int j = 0; j < 10; ++j)
#pragma unroll
    for (int off = 32; off; off >>= 1) part[j] += __shfl_xor(part[j], off);
  float mx = -1e30f;
#pragma unroll
  for (int j = 0; j < 10; ++j) { part[j] += bc[j]; mx = fmaxf(mx, part[j]); }
  float s = 0.f;
#pragma unroll
  for (int j = 0; j < 10; ++j) { part[j] = __expf(part[j] - mx); s += part[j]; }
  const float inv = 1.f / s;
#pragma unroll
  for (int i = 0; i < 12; ++i) {
    const int d = lane + 64 * i;
    float acc = 0.f;
#pragma unroll
    for (int j = 0; j < 10; ++j) acc = fmaf(part[j], cen_s[j * EMB + d], acc);
    qh_bf[base + d] = f2bf(x[i] + acc * inv);
  }
}

// ------------------------------------------------------------- CSR build
__global__ void hist_all(const int* __restrict__ gd, const int* __restrict__ d1,
                         const int* __restrict__ d2, int* __restrict__ cnt)
{
  int e = blockIdx.x * 256 + threadIdx.x;
  if (e < EG) atomicAdd(&cnt[gd[e]], 1);
  else if (e < EG + EI) atomicAdd(&cnt[QLEN + d1[e - EG]], 1);
  else if (e < EG + 2 * EI) atomicAdd(&cnt[QLEN + TLEN + d2[e - EG - EI]], 1);
}

__global__ __launch_bounds__(1024) void scan3(
    const int* __restrict__ cnt_all, int* __restrict__ rp_g,
    int* __restrict__ rp_1, int* __restrict__ rp_2, int* __restrict__ cur_all)
{
  __shared__ int buf[1024];
  const int b = blockIdx.x;
  const int n = (b == 0) ? QLEN : TLEN;
  const int seg = (b == 0) ? 0 : (b == 1) ? QLEN : QLEN + TLEN;
  const int* cnt = cnt_all + seg;
  int* cur = cur_all + seg;
  int* rowptr = (b == 0) ? rp_g : (b == 1) ? rp_1 : rp_2;
  const int tid = threadIdx.x;
  const int chunk = (n + 1023) >> 10;
  const int base = tid * chunk;
  int s = 0;
  for (int i = 0; i < chunk; ++i) {
    int idx = base + i;
    if (idx < n) s += cnt[idx];
  }
  buf[tid] = s;
  __syncthreads();
  for (int off = 1; off < 1024; off <<= 1) {
    int v = (tid >= off) ? buf[tid - off] : 0;
    __syncthreads();
    buf[tid] += v;
    __syncthreads();
  }
  int run = (tid == 0) ? 0 : buf[tid - 1];
  for (int i = 0; i < chunk; ++i) {
    int idx = base + i;
    if (idx < n) {
      rowptr[idx] = run;
      cur[idx] = run;
      run += cnt[idx];
    }
  }
  if (tid == 1023) rowptr[n] = buf[1023];
}

__global__ void fill_all(const int* __restrict__ gs, const int* __restrict__ gd,
                         const int* __restrict__ s1, const int* __restrict__ d1,
                         const int* __restrict__ s2, const int* __restrict__ d2,
                         int* __restrict__ cur_all, int* __restrict__ adj_all)
{
  int e = blockIdx.x * 256 + threadIdx.x;
  if (e < EG) {
    int p = atomicAdd(&cur_all[gd[e]], 1);
    adj_all[p] = gs[e];
  } else if (e < EG + EI) {
    int p = atomicAdd(&cur_all[QLEN + d1[e - EG]], 1);
    adj_all[EG + p] = s1[e - EG];
  } else if (e < EG + 2 * EI) {
    int p = atomicAdd(&cur_all[QLEN + TLEN + d2[e - EG - EI]], 1);
    adj_all[EG + EI + p] = s2[e - EG - EI];
  }
}

// --------------------- fused gathers: waves [0,QLEN) give, [QLEN,+TLEN) inter
__global__ __launch_bounds__(256) void gather_all(
    const u8* __restrict__ q, const u8* __restrict__ kv_g,
    const int* __restrict__ rp_g, const int* __restrict__ adj_g,
    const float* __restrict__ pri_g, u16* __restrict__ hq_bf,
    const u16* __restrict__ q_tag, const u8* __restrict__ kv1,
    const u8* __restrict__ kv2,
    const int* __restrict__ rp1, const int* __restrict__ adj1,
    const int* __restrict__ rp2, const int* __restrict__ adj2,
    const float* __restrict__ pri1, const float* __restrict__ pri2,
    u16* __restrict__ htag_bf)
{
  const int wid = blockIdx.x * 4 + (threadIdx.x >> 6);
  const int lane = threadIdx.x & 63;
  const int h = lane >> 4, sub = lane & 15;
  const int off = h * DKH + sub * 12;

  if (wid < QLEN) {
    const int d = wid;
    const int rs = rp_g[d], re = rp_g[d + 1];
    if (rs == re) return;
    const float pri = pri_g[h] * SCALE;
    float qv[3][12];
#pragma unroll
    for (int c = 0; c < 3; ++c)
      decode12((const u32*)(q + (size_t)(c * QLEN + d) * EMB + off), qv[c]);
    float S[3] = {0.f, 0.f, 0.f};
    float A[3][12] = {};
    auto edge = [&](int sn) {
      float kf[12], vf[12];
      decode12((const u32*)(kv_g + (size_t)sn * 1536 + off), kf);
      decode12((const u32*)(kv_g + (size_t)sn * 1536 + 768 + off), vf);
      float dt[3] = {0.f, 0.f, 0.f};
#pragma unroll
      for (int t = 0; t < 12; ++t) {
#pragma unroll
        for (int c = 0; c < 3; ++c) dt[c] = fmaf(qv[c][t], kf[t], dt[c]);
      }
#pragma unroll
      for (int c = 0; c < 3; ++c) {
#pragma unroll
        for (int o2 = 8; o2; o2 >>= 1) dt[c] += __shfl_xor(dt[c], o2);
        const float e = __expf(dt[c] * pri);
        S[c] += e;
#pragma unroll
        for (int t = 0; t < 12; ++t) A[c][t] = fmaf(e, vf[t], A[c][t]);
      }
    };
    __builtin_amdgcn_s_setprio(1);
    int i = rs;
    for (; i + 1 < re; i += 2) { edge(adj_g[i]); edge(adj_g[i + 1]); }
    if (i < re) edge(adj_g[i]);
    __builtin_amdgcn_s_setprio(0);
#pragma unroll
    for (int c = 0; c < 3; ++c) {
      const float inv = 1.f / S[c];
      u32* o = (u32*)(hq_bf + (size_t)(c * QLEN + d) * EMB + off);
#pragma unroll
      for (int t = 0; t < 6; ++t) {
        f32x2 r = bfx2(o[t]);
        r[0] += A[c][2 * t] * inv;
        r[1] += A[c][2 * t + 1] * inv;
        o[t] = (u32)f2bf(r[0]) | ((u32)f2bf(r[1]) << 16);
      }
    }
  } else {
    const int d = wid - QLEN;
    if (d >= TLEN) return;
    const int rs1 = rp1[d], re1 = rp1[d + 1];
    const int rs2 = rp2[d], re2 = rp2[d + 1];
    if (rs1 == re1 && rs2 == re2) return;
    float qv[12];
    {
      const u32* qp = (const u32*)(q_tag + (size_t)d * EMB + off);
#pragma unroll
      for (int t = 0; t < 6; ++t) {
        f32x2 r = bfx2(qp[t]);
        qv[2 * t] = r[0]; qv[2 * t + 1] = r[1];
      }
    }
    float R[12] = {};
#pragma unroll
    for (int rel = 0; rel < 2; ++rel) {
      const u8* kv = rel ? kv2 : kv1;
      const int rs = rel ? rs2 : rs1, re = rel ? re2 : re1;
      const int* adj = rel ? adj2 : adj1;
      if (rs == re) continue;
      const float pri = (rel ? pri2[h] : pri1[h]) * SCALE;
      float S = 0.f, A[12] = {};
      auto edge = [&](int sn) {
        float kf[12], vf[12];
        decode12((const u32*)(kv + (size_t)sn * 1536 + off), kf);
        decode12((const u32*)(kv + (size_t)sn * 1536 + 768 + off), vf);
        float dt = 0.f;
#pragma unroll
        for (int t = 0; t < 12; ++t) dt = fmaf(qv[t], kf[t], dt);
#pragma unroll
        for (int o2 = 8; o2; o2 >>= 1) dt += __shfl_xor(dt, o2);
        const float e = __expf(dt * pri);
        S += e;
#pragma unroll
        for (int t = 0; t < 12; ++t) A[t] = fmaf(e, vf[t], A[t]);
      };
      __builtin_amdgcn_s_setprio(1);
      int i = rs;
      for (; i + 1 < re; i += 2) { edge(adj[i]); edge(adj[i + 1]); }
      if (i < re) edge(adj[i]);
      __builtin_amdgcn_s_setprio(0);
      const float inv = 0.5f / S;
#pragma unroll
      for (int t = 0; t < 12; ++t) R[t] = fmaf(A[t], inv, R[t]);
    }
    u32* o = (u32*)(htag_bf + (size_t)d * EMB + off);
#pragma unroll
    for (int t = 0; t < 6; ++t) {
      f32x2 r = bfx2(o[t]);
      r[0] += R[2 * t];
      r[1] += R[2 * t + 1];
      o[t] = (u32)f2bf(r[0]) | ((u32)f2bf(r[1]) << 16);
    }
  }
}

}  // namespace

extern "C" void kernel_launch(void* const* d_in, const int* in_sizes, int n_in,
                              void* d_out, int out_size, void* d_ws, size_t ws_size,
                              hipStream_t stream)
{
  const float* q_emb   = (const float*)d_in[0];
  const float* t_emb   = (const float*)d_in[1];
  const int*   give_src = (const int*)d_in[2];
  const int*   give_dst = (const int*)d_in[3];
  const int*   i1_src  = (const int*)d_in[4];
  const int*   i1_dst  = (const int*)d_in[5];
  const int*   i2_src  = (const int*)d_in[6];
  const int*   i2_dst  = (const int*)d_in[7];
  const float* Wq_enc  = (const float*)d_in[8];
  const float* bq_enc  = (const float*)d_in[9];
  const float* Wc      = (const float*)d_in[10];
  const float* bc      = (const float*)d_in[11];
  const float* centers = (const float*)d_in[12];
  const float* kW      = (const float*)d_in[13];
  const float* kb      = (const float*)d_in[14];
  const float* qW      = (const float*)d_in[15];
  const float* qb      = (const float*)d_in[16];
  const float* vW      = (const float*)d_in[17];
  const float* vb      = (const float*)d_in[18];
  const float* rel_att = (const float*)d_in[19];
  const float* rel_msg = (const float*)d_in[20];
  const float* rel_pri = (const float*)d_in[21];
  const float* Wout    = (const float*)d_in[22];
  const float* bout    = (const float*)d_in[23];
  float* out = (float*)d_out;

  // -------- workspace carve-up
  float* p = (float*)d_ws;
  auto take = [&](size_t n) { float* r = p; p += ((n + 3) & ~(size_t)3); return r; };
  u16* h_q_bf    = (u16*)take((size_t)NQ * EMB / 2);
  u16* h_tag_bf  = (u16*)take((size_t)TLEN * EMB / 2);
  u16* q_emb_bf  = (u16*)take((size_t)QLEN * EMB / 2);
  u16* q_tag_bf  = (u16*)take((size_t)TLEN * EMB / 2);
  u8* kv_all     = (u8*)take((size_t)3 * TLEN * 1536 / 4);
  u8* kv_g = kv_all;
  u8* kv_1 = kv_all + (size_t)TLEN * 1536;
  u8* kv_2 = kv_all + (size_t)2 * TLEN * 1536;
  u16* WqT   = (u16*)take((size_t)3 * WS / 2);
  u16* qWT   = (u16*)take((size_t)4 * WS / 2);
  u16* WoutT = (u16*)take((size_t)WS / 2);
  u16* relWT = (u16*)take((size_t)48 * RS / 2);
  u16* kWbf  = (u16*)take((size_t)4 * WS / 2);
  u16* vWbf  = (u16*)take((size_t)4 * WS / 2);
  u16* Wcomb = (u16*)take((size_t)6 * 1536 * 768 / 2);
  float* bcomb = take(6 * 1536);
  float* WcT   = take(7680);
  int* rp_g  = (int*)take(QLEN + 1);
  int* rp_1  = (int*)take(TLEN + 1);
  int* rp_2  = (int*)take(TLEN + 1);
  int* cur_all = (int*)take(QLEN + 2 * TLEN);
  int* cnt_all = (int*)take(QLEN + 2 * TLEN);
  int* adj_all = (int*)take(EG + 2 * EI);
  int* adj_g = adj_all;
  int* adj_1 = adj_all + EG;
  int* adj_2 = adj_all + EG + EI;
  u8* q_que = (u8*)out;   // d_out as scratch (fp8); fully overwritten at end

  // -------- CSR builds (4 launches)
  hipMemsetAsync(cnt_all, 0, (size_t)(QLEN + 2 * TLEN) * sizeof(int), stream);
  hist_all<<<(EG + 2 * EI + 255) / 256, 256, 0, stream>>>(give_dst, i1_dst, i2_dst, cnt_all);
  scan3<<<3, 1024, 0, stream>>>(cnt_all, rp_g, rp_1, rp_2, cur_all);
  fill_all<<<(EG + 2 * EI + 255) / 256, 256, 0, stream>>>(
      give_src, give_dst, i1_src, i1_dst, i2_src, i2_dst, cur_all, adj_all);

  // -------- fused prologue: transposes + casts + packs (1 launch)
  {
    PrepArgs P;
    P.Wq_enc = Wq_enc; P.qW = qW; P.Wout = Wout; P.kW = kW; P.vW = vW;
    P.rel_att = rel_att; P.rel_msg = rel_msg; P.Wc = Wc; P.kb = kb; P.vb = vb;
    P.q_emb = q_emb; P.t_emb = t_emb;
    P.WqT = WqT; P.qWT = qWT; P.WoutT = WoutT; P.relWT = relWT;
    P.kWbf = kWbf; P.vWbf = vWbf; P.q_emb_bf = q_emb_bf; P.h_tag_bf = h_tag_bf;
    P.WcT = WcT; P.bcomb = bcomb;
    prep_all<<<20760, 256, 0, stream>>>(P);
  }
  // combined relation weights: Wcomb[lr][kv*768+h*192+n'][d] (bf16)
  gemm_bf16<0, 1, 1><<<dim3(6, 2, 48), 256, 0, stream>>>(
      relWT, DKH, 0, kWbf, EMB, 0, Wcomb, EMB, 0, nullptr, vWbf, DKH, EMB, DKH);

  // -------- question encoder + clustering
  gemm_bf16<1, 1, 0><<<dim3(18, 79, 1), 256, 0, stream>>>(
      q_emb_bf, EMB, 0, WqT, EMB, 0, h_q_bf, EMB, 0, bq_enc, q_emb_bf,
      QLEN, EMB * HNEED, EMB);
  assign_center512<<<NQ / 8, 512, 0, stream>>>(h_q_bf, WcT, bc, centers);

  for (int l = 0; l < 2; ++l) {
    PackJobs J;
    J.A[0] = h_tag_bf; J.Bt[0] = qWT + (long long)(l * 2) * WS; J.C[0] = q_tag_bf;
    J.bias[0] = qb + (l * 2) * EMB; J.M[0] = TLEN; J.nx[0] = 6; J.ldc[0] = 768; J.out[0] = 1;
    J.A[1] = h_q_bf; J.Bt[1] = qWT + (long long)(l * 2 + 1) * WS; J.C[1] = q_que;
    J.bias[1] = qb + (l * 2 + 1) * EMB; J.M[1] = NQ; J.nx[1] = 6; J.ldc[1] = 768; J.out[1] = 2;
    for (int r = 0; r < 3; ++r) {
      J.A[2 + r] = h_tag_bf;
      J.Bt[2 + r] = Wcomb + (long long)(l * 3 + r) * 1536 * 768;
      J.C[2 + r] = kv_all + (size_t)r * TLEN * 1536;
      J.bias[2 + r] = bcomb + (l * 3 + r) * 1536;
      J.M[2 + r] = TLEN; J.nx[2 + r] = 12; J.ldc[2 + r] = 1536; J.out[2 + r] = 2;
    }
    J.start[0] = 0;
    J.start[1] = 144;
    J.start[2] = 144 + 1410;
    J.start[3] = 1554 + 288;
    J.start[4] = 1842 + 288;
    J.start[5] = 2130 + 288;
    gemm_pack<<<2418, 256, 0, stream>>>(J);

    gather_all<<<(QLEN + TLEN) / 4 + 1, 256, 0, stream>>>(
        q_que, kv_g, rp_g, adj_g, rel_pri + (l * 3 + 0) * NHEADS, h_q_bf,
        q_tag_bf, kv_1, kv_2, rp_1, adj_1, rp_2, adj_2,
        rel_pri + (l * 3 + 1) * NHEADS, rel_pri + (l * 3 + 2) * NHEADS,
        h_tag_bf);
  }

  // -------- merged output GEMM
  gemm_bf16<2, 0, 0><<<dim3(6, 258, 1), 256, 0, stream>>>(
      h_q_bf, EMB, 0, WoutT, EMB, 0, out, EMB, 0, bout, nullptr,
      NQ + TLEN, EMB, EMB);
}